// Round 1
// 2068.818 us; speedup vs baseline: 2.4513x; 2.4513x over previous
//
#include <hip/hip_runtime.h>
#include <cstdint>
#include <cstddef>

// ---------- constants ----------
#define CL 6
#define CH 12
#define CD 768
#define CDH 64
#define CF 3072
#define CV 32000
#define CS 1024
#define CB 2
#define CM (CB*CS)   // 2048 token rows

typedef unsigned short u16;
typedef __bf16 bf16x8 __attribute__((ext_vector_type(8)));
typedef float f32x4 __attribute__((ext_vector_type(4)));

__device__ __forceinline__ float bf2f(u16 u) {
  union { unsigned int i; float f; } c; c.i = ((unsigned int)u) << 16; return c.f;
}
__device__ __forceinline__ u16 f2bf(float f) {
  union { float f; unsigned int i; } c; c.f = f;
  unsigned int lsb = (c.i >> 16) & 1u;
  c.i += 0x7fffu + lsb;            // round-to-nearest-even
  return (u16)(c.i >> 16);
}

// ---------- fp32 -> bf16 convert (for head weight emb) ----------
__global__ __launch_bounds__(256) void convert_kernel(
    const float* __restrict__ src, u16* __restrict__ dst, int total)
{
  int idx = blockIdx.x * 256 + threadIdx.x;
  if (idx < total) dst[idx] = f2bf(src[idx]);
}

// ---------- embedding: x[m,d] = emb[X[m],d] + pos[s,d] (fp32 in/out) ----------
__global__ __launch_bounds__(256) void embed_kernel(
    const int* __restrict__ X, const float* __restrict__ emb,
    const float* __restrict__ pos, float* __restrict__ x)
{
  int idx = blockIdx.x * 256 + threadIdx.x;      // grid covers exactly CM*CD
  int m = idx / CD, d = idx - m * CD;
  int s = m & (CS - 1);
  x[idx] = emb[(size_t)X[m] * CD + d] + pos[s * CD + d];
}

// ---------- layernorm (fp32 in, bf16 out), one block per row ----------
__global__ __launch_bounds__(256) void ln_kernel(
    const float* __restrict__ x, const float* __restrict__ gs,
    const float* __restrict__ gb, u16* __restrict__ out)
{
  __shared__ float red[256];
  int row = blockIdx.x, tid = threadIdx.x;
  const float* xr = x + (size_t)row * CD;
  float s = 0.f;
  for (int i = tid; i < CD; i += 256) s += xr[i];
  red[tid] = s; __syncthreads();
  for (int st = 128; st > 0; st >>= 1) { if (tid < st) red[tid] += red[tid + st]; __syncthreads(); }
  float mu = red[0] * (1.f / CD); __syncthreads();
  float v = 0.f;
  for (int i = tid; i < CD; i += 256) { float d = xr[i] - mu; v += d * d; }
  red[tid] = v; __syncthreads();
  for (int st = 128; st > 0; st >>= 1) { if (tid < st) red[tid] += red[tid + st]; __syncthreads(); }
  float inv = rsqrtf(red[0] * (1.f / CD) + 1e-5f);
  u16* orow = out + (size_t)row * CD;
  for (int i = tid; i < CD; i += 256)
    orow[i] = f2bf((xr[i] - mu) * inv * gs[i] + gb[i]);
}

// ---------- transpose repack + downcast: dst[b][c][r] = bf16(src[b][r][c]) ----------
__global__ __launch_bounds__(256) void repackT_kernel(
    u16* __restrict__ dst, const float* __restrict__ src, int R, int C, int total)
{
  int idx = blockIdx.x * 256 + threadIdx.x;
  if (idx >= total) return;
  int rc = R * C;
  int bb = idx / rc, rem = idx - bb * rc;
  int c = rem / R, rr = rem - c * R;
  dst[idx] = f2bf(src[(size_t)bb * rc + (size_t)rr * C + c]);
}

// ---------- MFMA GEMM: C(MxN) = A(MxK,bf16) * Bt(NxK,bf16) + bias [+res][relu] ----------
// 64x64 tile, BK=32, 4 waves, mfma_f32_16x16x32_bf16.
template<bool RES, bool RELU, bool OUTBF>
__global__ __launch_bounds__(256) void gemm_kernel(
    const u16* __restrict__ A, const u16* __restrict__ Bt,
    const float* __restrict__ bias, const float* __restrict__ res,
    void* __restrict__ outp, int M, int N, int K)
{
  __shared__ __align__(16) u16 As[64 * 32];
  __shared__ __align__(16) u16 Bs[64 * 32];
  int tid = threadIdx.x;
  int m0 = blockIdx.y * 64, n0 = blockIdx.x * 64;
  int wid = tid >> 6, lane = tid & 63;
  int quad = lane >> 4, l16 = lane & 15;
  int wm = (wid >> 1) * 32, wn = (wid & 1) * 32;
  int r = tid >> 2, c8 = (tid & 3) * 8;     // staging: 64 rows x 32 cols, 8 bf16/thread

  f32x4 zero = {0.f, 0.f, 0.f, 0.f};
  f32x4 acc[2][2];
  acc[0][0] = zero; acc[0][1] = zero; acc[1][0] = zero; acc[1][1] = zero;

  for (int kt = 0; kt < K; kt += 32) {
    uint4 av = *(const uint4*)(A  + (size_t)(m0 + r) * K + kt + c8);
    uint4 bv = *(const uint4*)(Bt + (size_t)(n0 + r) * K + kt + c8);
    __syncthreads();
    *(uint4*)&As[r * 32 + c8] = av;
    *(uint4*)&Bs[r * 32 + c8] = bv;
    __syncthreads();
    bf16x8 af[2], bfr[2];
#pragma unroll
    for (int i = 0; i < 2; i++) {
      af[i]  = *reinterpret_cast<const bf16x8*>(&As[(wm + i * 16 + l16) * 32 + quad * 8]);
      bfr[i] = *reinterpret_cast<const bf16x8*>(&Bs[(wn + i * 16 + l16) * 32 + quad * 8]);
    }
#pragma unroll
    for (int i = 0; i < 2; i++)
#pragma unroll
      for (int j = 0; j < 2; j++)
        acc[i][j] = __builtin_amdgcn_mfma_f32_16x16x32_bf16(af[i], bfr[j], acc[i][j], 0, 0, 0);
  }

#pragma unroll
  for (int i = 0; i < 2; i++) {
    int gmb = m0 + wm + i * 16 + quad * 4;
#pragma unroll
    for (int j = 0; j < 2; j++) {
      int gn = n0 + wn + j * 16 + l16;
      float bsv = bias[gn];
#pragma unroll
      for (int rr = 0; rr < 4; rr++) {
        float val = acc[i][j][rr] + bsv;
        if (RELU) val = fmaxf(val, 0.f);
        size_t o = (size_t)(gmb + rr) * N + gn;
        if (RES) val += res[o];
        if (OUTBF) ((u16*)outp)[o] = f2bf(val);
        else       ((float*)outp)[o] = val;
      }
    }
  }
}

// ---------- MFMA flash attention ----------
// Block: 64 Q-rows x one (b,h). 4 waves x 16 Q-rows each. KV tiles of 64.
// Fragment conventions identical to gemm_kernel (harness-verified):
//   A-frag: row = l16 (within 16-row tile), k = quad*8..+8
//   B-frag: Bt row-major [N][K], row n = l16, k = quad*8..+8
//   C/D:    col = l16, row = quad*4 + r
// LDS tiles XOR-swizzled: chunk' = chunk ^ (row&7)  (chunk = 8 u16 = 16 B)
// -> fragment ds_read_b128 is 2-way (free); row-major would be 16-way.
__global__ __launch_bounds__(256) void attn_mfma_kernel(
    const u16* __restrict__ q, const u16* __restrict__ k,
    const u16* __restrict__ v, u16* __restrict__ o)
{
  __shared__ __align__(16) u16 Ks[64 * 64];        // K tile  [t][d] swizzled
  __shared__ __align__(16) u16 Vt[64 * 64];        // V tile transposed [d][t] swizzled
  __shared__ __align__(16) u16 Ps[4 * 16 * 64];    // per-wave P [q][t] swizzled

  int tid = threadIdx.x;
  int qb = (CS / 64 - 1) - blockIdx.x;             // reversed: heavy causal blocks first
  int h = blockIdx.y, b = blockIdx.z;
  int wid = tid >> 6, lane = tid & 63, quad = lane >> 4, l16 = lane & 15;
  int q0 = qb * 64;
  size_t bh = (size_t)b * CS * CD + (size_t)h * CDH;   // layout [(b*S+s)*768 + h*64 + d]

  // Q A-fragments straight from global (one-time): row = q0+wid*16+l16, k = ks*32+quad*8
  bf16x8 aq[2];
  {
    const u16* qrow = q + bh + (size_t)(q0 + wid * 16 + l16) * CD;
#pragma unroll
    for (int ks = 0; ks < 2; ks++) {
      uint4 t = *(const uint4*)(qrow + ks * 32 + quad * 8);
      aq[ks] = *reinterpret_cast<bf16x8*>(&t);
    }
  }

  f32x4 oacc[4];
  float mrow[4], lrow[4];
#pragma unroll
  for (int j = 0; j < 4; j++) oacc[j] = f32x4{0.f, 0.f, 0.f, 0.f};
#pragma unroll
  for (int r = 0; r < 4; r++) { mrow[r] = -1e30f; lrow[r] = 0.f; }

  int srow = tid >> 3, schunk = tid & 7;   // K staging: 32 rows/iter x 8 chunks
  int vrow = tid >> 2, vseg = (tid & 3) * 16;  // V staging: row t, 16 d each

  for (int t0 = 0; t0 <= q0; t0 += 64) {
    __syncthreads();   // previous tile's LDS reads done
    // ---- stage K tile (vectorized, swizzled) ----
#pragma unroll
    for (int it = 0; it < 2; it++) {
      int row = srow + it * 32;
      uint4 kv4 = *(const uint4*)(k + bh + (size_t)(t0 + row) * CD + schunk * 8);
      *(uint4*)&Ks[row * 64 + ((schunk ^ (row & 7)) * 8)] = kv4;
    }
    // ---- stage V transposed (scalar writes, swizzled) ----
    {
      const u16* vr = v + bh + (size_t)(t0 + vrow) * CD + vseg;
      uint4 a0 = *(const uint4*)(vr);
      uint4 a1 = *(const uint4*)(vr + 8);
      int c = vrow >> 3, w7 = vrow & 7;
#pragma unroll
      for (int i = 0; i < 16; i++) {
        int d = vseg + i;
        u16 val = (i < 8) ? ((const u16*)&a0)[i] : ((const u16*)&a1)[i - 8];
        Vt[d * 64 + (((c ^ (d & 7)) * 8) | w7)] = val;
      }
    }
    __syncthreads();   // staging complete

    // ---- S = Q K^T (per wave: 16q x 64t) ----
    f32x4 sacc[4];
#pragma unroll
    for (int j = 0; j < 4; j++) sacc[j] = f32x4{0.f, 0.f, 0.f, 0.f};
#pragma unroll
    for (int j = 0; j < 4; j++) {
      int row = j * 16 + l16;
#pragma unroll
      for (int ks = 0; ks < 2; ks++) {
        bf16x8 bk = *reinterpret_cast<const bf16x8*>(
            &Ks[row * 64 + ((((ks * 4 + quad) ^ (row & 7)) * 8))]);
        sacc[j] = __builtin_amdgcn_mfma_f32_16x16x32_bf16(aq[ks], bk, sacc[j], 0, 0, 0);
      }
    }

    // ---- scale + causal mask ----
    int qg0 = q0 + wid * 16 + quad * 4;   // q_glob for r=0
#pragma unroll
    for (int j = 0; j < 4; j++) {
      int tg = t0 + j * 16 + l16;
#pragma unroll
      for (int r = 0; r < 4; r++) {
        float s = sacc[j][r] * 0.125f;     // 1/sqrt(64)
        sacc[j][r] = (tg <= qg0 + r) ? s : -1e30f;
      }
    }

    // ---- online softmax (rows live on quad*4+r; t across l16 lanes + 4 reg-tiles) ----
#pragma unroll
    for (int r = 0; r < 4; r++) {
      float m = fmaxf(fmaxf(sacc[0][r], sacc[1][r]), fmaxf(sacc[2][r], sacc[3][r]));
#pragma unroll
      for (int sh = 1; sh < 16; sh <<= 1) m = fmaxf(m, __shfl_xor(m, sh, 64));
      float mnew = fmaxf(mrow[r], m);
      float scal = __expf(mrow[r] - mnew);
      mrow[r] = mnew;
      lrow[r] *= scal;
#pragma unroll
      for (int j = 0; j < 4; j++) oacc[j][r] *= scal;
      float sum = 0.f;
#pragma unroll
      for (int j = 0; j < 4; j++) {
        float p = __expf(sacc[j][r] - mnew);
        sacc[j][r] = p;
        sum += p;
      }
#pragma unroll
      for (int sh = 1; sh < 16; sh <<= 1) sum += __shfl_xor(sum, sh, 64);
      lrow[r] += sum;
    }

    // ---- P -> LDS (bf16, per-wave region, swizzled) ----
    u16* Pw = Ps + wid * 1024;
#pragma unroll
    for (int j = 0; j < 4; j++) {
      int c = (l16 >> 3) + 2 * j;
#pragma unroll
      for (int r = 0; r < 4; r++) {
        int row = quad * 4 + r;
        Pw[row * 64 + (((c ^ (row & 7)) * 8) | (l16 & 7))] = f2bf(sacc[j][r]);
      }
    }

    // ---- O += P V  (A = P[16q x 64t], Bt = Vt[64d x 64t]) ----
    bf16x8 ap[2];
#pragma unroll
    for (int ks = 0; ks < 2; ks++)
      ap[ks] = *reinterpret_cast<const bf16x8*>(
          &Pw[l16 * 64 + ((((ks * 4 + quad) ^ (l16 & 7)) * 8))]);
#pragma unroll
    for (int j = 0; j < 4; j++) {
      int row = j * 16 + l16;
#pragma unroll
      for (int ks = 0; ks < 2; ks++) {
        bf16x8 bv = *reinterpret_cast<const bf16x8*>(
            &Vt[row * 64 + ((((ks * 4 + quad) ^ (row & 7)) * 8))]);
        oacc[j] = __builtin_amdgcn_mfma_f32_16x16x32_bf16(ap[ks], bv, oacc[j], 0, 0, 0);
      }
    }
  }

  // ---- epilogue: O / l -> bf16 ----
#pragma unroll
  for (int r = 0; r < 4; r++) {
    float inv = 1.f / lrow[r];
    int qg = q0 + wid * 16 + quad * 4 + r;
    u16* orow = o + bh + (size_t)qg * CD;
#pragma unroll
    for (int j = 0; j < 4; j++)
      orow[j * 16 + l16] = f2bf(oacc[j][r] * inv);
  }
}

// ---------- launcher ----------
extern "C" void kernel_launch(void* const* d_in, const int* in_sizes, int n_in,
                              void* d_out, int out_size, void* d_ws, size_t ws_size,
                              hipStream_t stream) {
  const int*   X      = (const int*)d_in[0];
  const float* emb    = (const float*)d_in[1];
  const float* pos    = (const float*)d_in[2];
  const float* Wq     = (const float*)d_in[3];
  const float* bq     = (const float*)d_in[4];
  const float* Wk     = (const float*)d_in[5];
  const float* bk     = (const float*)d_in[6];
  const float* Wv     = (const float*)d_in[7];
  const float* bv     = (const float*)d_in[8];
  const float* Wo     = (const float*)d_in[9];
  const float* bo     = (const float*)d_in[10];
  const float* ln1s   = (const float*)d_in[11];
  const float* ln1b   = (const float*)d_in[12];
  const float* ln2s   = (const float*)d_in[13];
  const float* ln2b   = (const float*)d_in[14];
  const float* W1     = (const float*)d_in[15];
  const float* b1     = (const float*)d_in[16];
  const float* W2     = (const float*)d_in[17];
  const float* b2     = (const float*)d_in[18];
  const float* lnfs   = (const float*)d_in[19];
  const float* lnfb   = (const float*)d_in[20];
  const float* headb  = (const float*)d_in[21];
  (void)in_sizes; (void)n_in; (void)out_size; (void)ws_size;

  char* ws = (char*)d_ws;
  size_t off = 0;
  auto alloc = [&](size_t bytes) { void* p = ws + off; off += (bytes + 255) & ~(size_t)255; return p; };

  float* x    = (float*)alloc((size_t)CM * CD * 4);
  u16*   xn   = (u16*)  alloc((size_t)CM * CD * 2);
  u16*   qb   = (u16*)  alloc((size_t)CM * CD * 2);
  u16*   kb   = (u16*)  alloc((size_t)CM * CD * 2);
  u16*   vb   = (u16*)  alloc((size_t)CM * CD * 2);
  u16*   ao   = (u16*)  alloc((size_t)CM * CD * 2);
  u16*   hb   = (u16*)  alloc((size_t)CM * CF * 2);
  u16*   Wqt  = (u16*)  alloc((size_t)CD * CD * 2);
  u16*   Wkt  = (u16*)  alloc((size_t)CD * CD * 2);
  u16*   Wvt  = (u16*)  alloc((size_t)CD * CD * 2);
  u16*   Wot  = (u16*)  alloc((size_t)CD * CD * 2);
  u16*   W1t  = (u16*)  alloc((size_t)CD * CF * 2);
  u16*   W2t  = (u16*)  alloc((size_t)CD * CF * 2);
  u16*   embC = (u16*)  alloc((size_t)CV * CD * 2);   // bf16 copy of emb for head GEMM

  embed_kernel<<<CM * CD / 256, 256, 0, stream>>>(X, emb, pos, x);
  convert_kernel<<<(CV * CD) / 256, 256, 0, stream>>>(emb, embC, CV * CD);

  const int QKV_TOT = CH * CD * CDH;        // 589824
  const int OO_TOT  = CD * CD;              // 589824
  const int FF_TOT  = CD * CF;              // 2359296

  for (int l = 0; l < CL; l++) {
    repackT_kernel<<<(QKV_TOT + 255) / 256, 256, 0, stream>>>(Wqt, Wq + (size_t)l * QKV_TOT, CD, CDH, QKV_TOT);
    repackT_kernel<<<(QKV_TOT + 255) / 256, 256, 0, stream>>>(Wkt, Wk + (size_t)l * QKV_TOT, CD, CDH, QKV_TOT);
    repackT_kernel<<<(QKV_TOT + 255) / 256, 256, 0, stream>>>(Wvt, Wv + (size_t)l * QKV_TOT, CD, CDH, QKV_TOT);
    repackT_kernel<<<(OO_TOT + 255) / 256, 256, 0, stream>>>(Wot, Wo + (size_t)l * OO_TOT, CD, CD, OO_TOT);
    repackT_kernel<<<(FF_TOT + 255) / 256, 256, 0, stream>>>(W1t, W1 + (size_t)l * FF_TOT, CD, CF, FF_TOT);
    repackT_kernel<<<(FF_TOT + 255) / 256, 256, 0, stream>>>(W2t, W2 + (size_t)l * FF_TOT, CF, CD, FF_TOT);

    ln_kernel<<<CM, 256, 0, stream>>>(x, ln1s + l * CD, ln1b + l * CD, xn);

    gemm_kernel<false, false, true><<<dim3(CD / 64, CM / 64), 256, 0, stream>>>(xn, Wqt, bq + l * CD, nullptr, qb, CM, CD, CD);
    gemm_kernel<false, false, true><<<dim3(CD / 64, CM / 64), 256, 0, stream>>>(xn, Wkt, bk + l * CD, nullptr, kb, CM, CD, CD);
    gemm_kernel<false, false, true><<<dim3(CD / 64, CM / 64), 256, 0, stream>>>(xn, Wvt, bv + l * CD, nullptr, vb, CM, CD, CD);

    attn_mfma_kernel<<<dim3(CS / 64, CH, CB), 256, 0, stream>>>(qb, kb, vb, ao);

    gemm_kernel<true, false, false><<<dim3(CD / 64, CM / 64), 256, 0, stream>>>(ao, Wot, bo + l * CD, x, x, CM, CD, CD);

    ln_kernel<<<CM, 256, 0, stream>>>(x, ln2s + l * CD, ln2b + l * CD, xn);

    gemm_kernel<false, true, true><<<dim3(CF / 64, CM / 64), 256, 0, stream>>>(xn, W1t, b1 + l * CF, nullptr, hb, CM, CF, CD);
    gemm_kernel<true, false, false><<<dim3(CD / 64, CM / 64), 256, 0, stream>>>(hb, W2t, b2 + l * CD, x, x, CM, CD, CF);
  }

  ln_kernel<<<CM, 256, 0, stream>>>(x, lnfs, lnfb, xn);
  gemm_kernel<false, false, false><<<dim3(CV / 64, CM / 64), 256, 0, stream>>>(xn, embC, headb, nullptr, d_out, CM, CV, CD);
}

// Round 2
// 1655.795 us; speedup vs baseline: 3.0628x; 1.2494x over previous
//
#include <hip/hip_runtime.h>
#include <cstdint>
#include <cstddef>

// ---------- constants ----------
#define CL 6
#define CH 12
#define CD 768
#define CDH 64
#define CF 3072
#define CV 32000
#define CS 1024
#define CB 2
#define CM (CB*CS)   // 2048 token rows
#define CQS 2304     // fused qkv row stride

typedef unsigned short u16;
typedef __bf16 bf16x8 __attribute__((ext_vector_type(8)));
typedef float f32x4 __attribute__((ext_vector_type(4)));

__device__ __forceinline__ float bf2f(u16 u) {
  union { unsigned int i; float f; } c; c.i = ((unsigned int)u) << 16; return c.f;
}
__device__ __forceinline__ u16 f2bf(float f) {
  union { float f; unsigned int i; } c; c.f = f;
  unsigned int lsb = (c.i >> 16) & 1u;
  c.i += 0x7fffu + lsb;            // round-to-nearest-even
  return (u16)(c.i >> 16);
}

// async global->LDS, 16B per lane; LDS dest = wave-uniform base + lane*16
__device__ __forceinline__ void gload16(const u16* g, u16* l) {
  __builtin_amdgcn_global_load_lds(
      (const __attribute__((address_space(1))) void*)g,
      (__attribute__((address_space(3))) void*)l, 16, 0, 0);
}

// ---------- fp32 -> bf16 convert (for head weight emb) ----------
__global__ __launch_bounds__(256) void convert_kernel(
    const float* __restrict__ src, u16* __restrict__ dst, int total)
{
  int idx = blockIdx.x * 256 + threadIdx.x;
  if (idx < total) dst[idx] = f2bf(src[idx]);
}

// ---------- embedding: x[m,d] = emb[X[m],d] + pos[s,d] (fp32 in/out) ----------
__global__ __launch_bounds__(256) void embed_kernel(
    const int* __restrict__ X, const float* __restrict__ emb,
    const float* __restrict__ pos, float* __restrict__ x)
{
  int idx = blockIdx.x * 256 + threadIdx.x;      // grid covers exactly CM*CD
  int m = idx / CD, d = idx - m * CD;
  int s = m & (CS - 1);
  x[idx] = emb[(size_t)X[m] * CD + d] + pos[s * CD + d];
}

// ---------- layernorm (fp32 in, bf16 out), one block per row ----------
__global__ __launch_bounds__(256) void ln_kernel(
    const float* __restrict__ x, const float* __restrict__ gs,
    const float* __restrict__ gb, u16* __restrict__ out)
{
  __shared__ float red[256];
  int row = blockIdx.x, tid = threadIdx.x;
  const float* xr = x + (size_t)row * CD;
  float s = 0.f;
  for (int i = tid; i < CD; i += 256) s += xr[i];
  red[tid] = s; __syncthreads();
  for (int st = 128; st > 0; st >>= 1) { if (tid < st) red[tid] += red[tid + st]; __syncthreads(); }
  float mu = red[0] * (1.f / CD); __syncthreads();
  float v = 0.f;
  for (int i = tid; i < CD; i += 256) { float d = xr[i] - mu; v += d * d; }
  red[tid] = v; __syncthreads();
  for (int st = 128; st > 0; st >>= 1) { if (tid < st) red[tid] += red[tid + st]; __syncthreads(); }
  float inv = rsqrtf(red[0] * (1.f / CD) + 1e-5f);
  u16* orow = out + (size_t)row * CD;
  for (int i = tid; i < CD; i += 256)
    orow[i] = f2bf((xr[i] - mu) * inv * gs[i] + gb[i]);
}

// ---------- coalesced transpose repack: dst[b][c][r] = bf16(src[b][r][c]) ----------
// 64r x 32c tile per block; phase1 coalesced fp32 reads -> LDS (store transposed,
// conflict-free stride 65); phase2 packs 4 bf16 -> 8B vectorized coalesced stores.
// Requires R % 64 == 0, C % 32 == 0.
__global__ __launch_bounds__(256) void trans_kernel(
    u16* __restrict__ dst, const float* __restrict__ src, int R, int C)
{
  __shared__ float st[32][65];   // st[c][r]
  int r0 = blockIdx.x * 64, c0 = blockIdx.y * 32, bz = blockIdx.z;
  const float* s = src + (size_t)bz * R * C;
  u16* d = dst + (size_t)bz * R * C;
  int tx = threadIdx.x & 31, ty = threadIdx.x >> 5;
#pragma unroll
  for (int i = 0; i < 8; i++) {
    int r = ty + 8 * i;
    st[tx][r] = s[(size_t)(r0 + r) * C + c0 + tx];
  }
  __syncthreads();
  int j = threadIdx.x & 15, cbase = threadIdx.x >> 4;
#pragma unroll
  for (int i = 0; i < 2; i++) {
    int c = cbase + 16 * i;
    uint2 pk;
    u16* p = (u16*)&pk;
    p[0] = f2bf(st[c][4 * j + 0]);
    p[1] = f2bf(st[c][4 * j + 1]);
    p[2] = f2bf(st[c][4 * j + 2]);
    p[3] = f2bf(st[c][4 * j + 3]);
    *(uint2*)&d[(size_t)(c0 + c) * R + r0 + 4 * j] = pk;
  }
}

// ---------- pack per-layer qkv bias: dst[l][0:768|768:1536|1536:2304] ----------
__global__ __launch_bounds__(256) void biaspack_kernel(
    const float* __restrict__ bq, const float* __restrict__ bk,
    const float* __restrict__ bv, float* __restrict__ dst)
{
  int idx = blockIdx.x * 256 + threadIdx.x;   // grid covers CL*2304 exactly
  int l = idx / CQS, c = idx - l * CQS;
  float val;
  if (c < 768)       val = bq[l * 768 + c];
  else if (c < 1536) val = bk[l * 768 + c - 768];
  else               val = bv[l * 768 + c - 1536];
  dst[idx] = val;
}

// ---------- MFMA GEMM 64x64 (kept for N=768 GEMMs: Wo, FF2) ----------
template<bool RES, bool RELU, bool OUTBF>
__global__ __launch_bounds__(256) void gemm_kernel(
    const u16* __restrict__ A, const u16* __restrict__ Bt,
    const float* __restrict__ bias, const float* __restrict__ res,
    void* __restrict__ outp, int M, int N, int K)
{
  __shared__ __align__(16) u16 As[64 * 32];
  __shared__ __align__(16) u16 Bs[64 * 32];
  int tid = threadIdx.x;
  int m0 = blockIdx.y * 64, n0 = blockIdx.x * 64;
  int wid = tid >> 6, lane = tid & 63;
  int quad = lane >> 4, l16 = lane & 15;
  int wm = (wid >> 1) * 32, wn = (wid & 1) * 32;
  int r = tid >> 2, c8 = (tid & 3) * 8;     // staging: 64 rows x 32 cols, 8 bf16/thread

  f32x4 zero = {0.f, 0.f, 0.f, 0.f};
  f32x4 acc[2][2];
  acc[0][0] = zero; acc[0][1] = zero; acc[1][0] = zero; acc[1][1] = zero;

  for (int kt = 0; kt < K; kt += 32) {
    uint4 av = *(const uint4*)(A  + (size_t)(m0 + r) * K + kt + c8);
    uint4 bv = *(const uint4*)(Bt + (size_t)(n0 + r) * K + kt + c8);
    __syncthreads();
    *(uint4*)&As[r * 32 + c8] = av;
    *(uint4*)&Bs[r * 32 + c8] = bv;
    __syncthreads();
    bf16x8 af[2], bfr[2];
#pragma unroll
    for (int i = 0; i < 2; i++) {
      af[i]  = *reinterpret_cast<const bf16x8*>(&As[(wm + i * 16 + l16) * 32 + quad * 8]);
      bfr[i] = *reinterpret_cast<const bf16x8*>(&Bs[(wn + i * 16 + l16) * 32 + quad * 8]);
    }
#pragma unroll
    for (int i = 0; i < 2; i++)
#pragma unroll
      for (int j = 0; j < 2; j++)
        acc[i][j] = __builtin_amdgcn_mfma_f32_16x16x32_bf16(af[i], bfr[j], acc[i][j], 0, 0, 0);
  }

#pragma unroll
  for (int i = 0; i < 2; i++) {
    int gmb = m0 + wm + i * 16 + quad * 4;
#pragma unroll
    for (int j = 0; j < 2; j++) {
      int gn = n0 + wn + j * 16 + l16;
      float bsv = bias[gn];
#pragma unroll
      for (int rr = 0; rr < 4; rr++) {
        float val = acc[i][j][rr] + bsv;
        if (RELU) val = fmaxf(val, 0.f);
        size_t o = (size_t)(gmb + rr) * N + gn;
        if (RES) val += res[o];
        if (OUTBF) ((u16*)outp)[o] = f2bf(val);
        else       ((float*)outp)[o] = val;
      }
    }
  }
}

// ---------- MFMA GEMM 128x128, BK=32, global_load_lds staging (m97 structure) ----------
// 4 waves, each computes a 64x64 quadrant (4x4 16x16x32 fragments).
// Linear LDS (T2 swizzle is null at 2-phase per regime gate).
// 1-D grid with bijective XCD chunking; bn-major order inside each chunk so the
// B panel streams once device-wide (head GEMM: 49 MB embC) while A stays L2-hot.
template<bool RES, bool RELU, bool OUTBF>
__global__ __launch_bounds__(256) void gemm128_kernel(
    const u16* __restrict__ A, const u16* __restrict__ Bt,
    const float* __restrict__ bias, const float* __restrict__ res,
    void* __restrict__ outp, int M, int N, int K)
{
  __shared__ __align__(16) u16 As[128 * 32];
  __shared__ __align__(16) u16 Bs[128 * 32];
  int tid = threadIdx.x;
  int nbm = M >> 7, nbn = N >> 7, nwg = nbm * nbn;
  int orig = blockIdx.x;
  int q8 = nwg >> 3, r8 = nwg & 7;
  int xcd = orig & 7;
  int t = ((xcd < r8) ? xcd * (q8 + 1) : r8 * (q8 + 1) + (xcd - r8) * q8) + (orig >> 3);
  int bm = t % nbm, bn = t / nbm;        // bn-major within chunk
  int m0 = bm << 7, n0 = bn << 7;

  int wv = tid >> 6, ln = tid & 63;
  int quad = ln >> 4, l16 = ln & 15;
  int wr = wv >> 1, wc = wv & 1;

  // staging: LDS chunk (16B) index = it*256 + wv*64 + lane; row = chunk>>2, col8 = (chunk&3)*8
  int srow = wv * 16 + (ln >> 2);
  int scol = (ln & 3) * 8;
  const u16* ga0 = A  + (size_t)(m0 + srow) * K + scol;
  const u16* ga1 = A  + (size_t)(m0 + srow + 64) * K + scol;
  const u16* gb0 = Bt + (size_t)(n0 + srow) * K + scol;
  const u16* gb1 = Bt + (size_t)(n0 + srow + 64) * K + scol;
  u16* lA0 = As + wv * 512;          // + lane*16B implicit
  u16* lA1 = As + 2048 + wv * 512;
  u16* lB0 = Bs + wv * 512;
  u16* lB1 = Bs + 2048 + wv * 512;

  f32x4 acc[4][4];
#pragma unroll
  for (int i = 0; i < 4; i++)
#pragma unroll
    for (int j = 0; j < 4; j++) acc[i][j] = f32x4{0.f, 0.f, 0.f, 0.f};

  for (int kt = 0; kt < K; kt += 32) {
    __syncthreads();                  // prev iter's ds_reads done before overwrite
    gload16(ga0 + kt, lA0);
    gload16(ga1 + kt, lA1);
    gload16(gb0 + kt, lB0);
    gload16(gb1 + kt, lB1);
    __syncthreads();                  // implies vmcnt(0): staged data visible
    bf16x8 af[4], bf[4];
#pragma unroll
    for (int i = 0; i < 4; i++)
      af[i] = *reinterpret_cast<const bf16x8*>(&As[(wr * 64 + i * 16 + l16) * 32 + quad * 8]);
#pragma unroll
    for (int j = 0; j < 4; j++)
      bf[j] = *reinterpret_cast<const bf16x8*>(&Bs[(wc * 64 + j * 16 + l16) * 32 + quad * 8]);
#pragma unroll
    for (int i = 0; i < 4; i++)
#pragma unroll
      for (int j = 0; j < 4; j++)
        acc[i][j] = __builtin_amdgcn_mfma_f32_16x16x32_bf16(af[i], bf[j], acc[i][j], 0, 0, 0);
  }

#pragma unroll
  for (int i = 0; i < 4; i++) {
    int gm = m0 + wr * 64 + i * 16 + quad * 4;
#pragma unroll
    for (int j = 0; j < 4; j++) {
      int gn = n0 + wc * 64 + j * 16 + l16;
      float bsv = bias[gn];
#pragma unroll
      for (int rr = 0; rr < 4; rr++) {
        float val = acc[i][j][rr] + bsv;
        if (RELU) val = fmaxf(val, 0.f);
        size_t oo = (size_t)(gm + rr) * N + gn;
        if (RES) val += res[oo];
        if (OUTBF) ((u16*)outp)[oo] = f2bf(val);
        else       ((float*)outp)[oo] = val;
      }
    }
  }
}

// ---------- MFMA flash attention (reads fused qkv buffer, stride 2304) ----------
// Block: 64 Q-rows x one (b,h). 4 waves x 16 Q-rows each. KV tiles of 64.
__global__ __launch_bounds__(256) void attn_mfma_kernel(
    const u16* __restrict__ qkv, u16* __restrict__ o)
{
  __shared__ __align__(16) u16 Ks[64 * 64];        // K tile  [t][d] swizzled
  __shared__ __align__(16) u16 Vt[64 * 64];        // V tile transposed [d][t] swizzled
  __shared__ __align__(16) u16 Ps[4 * 16 * 64];    // per-wave P [q][t] swizzled

  int tid = threadIdx.x;
  int qb = (CS / 64 - 1) - blockIdx.x;             // reversed: heavy causal blocks first
  int h = blockIdx.y, b = blockIdx.z;
  int wid = tid >> 6, lane = tid & 63, quad = lane >> 4, l16 = lane & 15;
  int q0 = qb * 64;
  size_t bh = (size_t)b * CS * CQS + h * CDH;      // fused layout [(b*S+s)*2304 + seg + h*64 + d]

  // Q A-fragments straight from global (one-time)
  bf16x8 aq[2];
  {
    const u16* qrow = qkv + bh + (size_t)(q0 + wid * 16 + l16) * CQS;
#pragma unroll
    for (int ks = 0; ks < 2; ks++) {
      uint4 t = *(const uint4*)(qrow + ks * 32 + quad * 8);
      aq[ks] = *reinterpret_cast<bf16x8*>(&t);
    }
  }

  f32x4 oacc[4];
  float mrow[4], lrow[4];
#pragma unroll
  for (int j = 0; j < 4; j++) oacc[j] = f32x4{0.f, 0.f, 0.f, 0.f};
#pragma unroll
  for (int r = 0; r < 4; r++) { mrow[r] = -1e30f; lrow[r] = 0.f; }

  int srow = tid >> 3, schunk = tid & 7;       // K staging: 32 rows/iter x 8 chunks
  int vrow = tid >> 2, vseg = (tid & 3) * 16;  // V staging: row t, 16 d each

  for (int t0 = 0; t0 <= q0; t0 += 64) {
    __syncthreads();   // previous tile's LDS reads done
    // ---- stage K tile (vectorized, swizzled) ----
#pragma unroll
    for (int it = 0; it < 2; it++) {
      int row = srow + it * 32;
      uint4 kv4 = *(const uint4*)(qkv + bh + 768 + (size_t)(t0 + row) * CQS + schunk * 8);
      *(uint4*)&Ks[row * 64 + ((schunk ^ (row & 7)) * 8)] = kv4;
    }
    // ---- stage V transposed (scalar writes, swizzled) ----
    {
      const u16* vr = qkv + bh + 1536 + (size_t)(t0 + vrow) * CQS + vseg;
      uint4 a0 = *(const uint4*)(vr);
      uint4 a1 = *(const uint4*)(vr + 8);
      int c = vrow >> 3, w7 = vrow & 7;
#pragma unroll
      for (int i = 0; i < 16; i++) {
        int d = vseg + i;
        u16 val = (i < 8) ? ((const u16*)&a0)[i] : ((const u16*)&a1)[i - 8];
        Vt[d * 64 + (((c ^ (d & 7)) * 8) | w7)] = val;
      }
    }
    __syncthreads();   // staging complete

    // ---- S = Q K^T (per wave: 16q x 64t) ----
    f32x4 sacc[4];
#pragma unroll
    for (int j = 0; j < 4; j++) sacc[j] = f32x4{0.f, 0.f, 0.f, 0.f};
#pragma unroll
    for (int j = 0; j < 4; j++) {
      int row = j * 16 + l16;
#pragma unroll
      for (int ks = 0; ks < 2; ks++) {
        bf16x8 bk = *reinterpret_cast<const bf16x8*>(
            &Ks[row * 64 + ((((ks * 4 + quad) ^ (row & 7)) * 8))]);
        sacc[j] = __builtin_amdgcn_mfma_f32_16x16x32_bf16(aq[ks], bk, sacc[j], 0, 0, 0);
      }
    }

    // ---- scale + causal mask ----
    int qg0 = q0 + wid * 16 + quad * 4;   // q_glob for r=0
#pragma unroll
    for (int j = 0; j < 4; j++) {
      int tg = t0 + j * 16 + l16;
#pragma unroll
      for (int r = 0; r < 4; r++) {
        float s = sacc[j][r] * 0.125f;     // 1/sqrt(64)
        sacc[j][r] = (tg <= qg0 + r) ? s : -1e30f;
      }
    }

    // ---- online softmax ----
#pragma unroll
    for (int r = 0; r < 4; r++) {
      float m = fmaxf(fmaxf(sacc[0][r], sacc[1][r]), fmaxf(sacc[2][r], sacc[3][r]));
#pragma unroll
      for (int sh = 1; sh < 16; sh <<= 1) m = fmaxf(m, __shfl_xor(m, sh, 64));
      float mnew = fmaxf(mrow[r], m);
      float scal = __expf(mrow[r] - mnew);
      mrow[r] = mnew;
      lrow[r] *= scal;
#pragma unroll
      for (int j = 0; j < 4; j++) oacc[j][r] *= scal;
      float sum = 0.f;
#pragma unroll
      for (int j = 0; j < 4; j++) {
        float p = __expf(sacc[j][r] - mnew);
        sacc[j][r] = p;
        sum += p;
      }
#pragma unroll
      for (int sh = 1; sh < 16; sh <<= 1) sum += __shfl_xor(sum, sh, 64);
      lrow[r] += sum;
    }

    // ---- P -> LDS (bf16, per-wave region, swizzled) ----
    u16* Pw = Ps + wid * 1024;
#pragma unroll
    for (int j = 0; j < 4; j++) {
      int c = (l16 >> 3) + 2 * j;
#pragma unroll
      for (int r = 0; r < 4; r++) {
        int row = quad * 4 + r;
        Pw[row * 64 + (((c ^ (row & 7)) * 8) | (l16 & 7))] = f2bf(sacc[j][r]);
      }
    }

    // ---- O += P V ----
    bf16x8 ap[2];
#pragma unroll
    for (int ks = 0; ks < 2; ks++)
      ap[ks] = *reinterpret_cast<const bf16x8*>(
          &Pw[l16 * 64 + ((((ks * 4 + quad) ^ (l16 & 7)) * 8))]);
#pragma unroll
    for (int j = 0; j < 4; j++) {
      int row = j * 16 + l16;
#pragma unroll
      for (int ks = 0; ks < 2; ks++) {
        bf16x8 bv = *reinterpret_cast<const bf16x8*>(
            &Vt[row * 64 + ((((ks * 4 + quad) ^ (row & 7)) * 8))]);
        oacc[j] = __builtin_amdgcn_mfma_f32_16x16x32_bf16(ap[ks], bv, oacc[j], 0, 0, 0);
      }
    }
  }

  // ---- epilogue: O / l -> bf16 (output stride CD) ----
#pragma unroll
  for (int r = 0; r < 4; r++) {
    float inv = 1.f / lrow[r];
    int qg = q0 + wid * 16 + quad * 4 + r;
    u16* orow = o + (size_t)b * CS * CD + h * CDH + (size_t)qg * CD;
#pragma unroll
    for (int j = 0; j < 4; j++)
      orow[j * 16 + l16] = f2bf(oacc[j][r] * inv);
  }
}

// ---------- launcher ----------
extern "C" void kernel_launch(void* const* d_in, const int* in_sizes, int n_in,
                              void* d_out, int out_size, void* d_ws, size_t ws_size,
                              hipStream_t stream) {
  const int*   X      = (const int*)d_in[0];
  const float* emb    = (const float*)d_in[1];
  const float* pos    = (const float*)d_in[2];
  const float* Wq     = (const float*)d_in[3];
  const float* bq     = (const float*)d_in[4];
  const float* Wk     = (const float*)d_in[5];
  const float* bk     = (const float*)d_in[6];
  const float* Wv     = (const float*)d_in[7];
  const float* bv     = (const float*)d_in[8];
  const float* Wo     = (const float*)d_in[9];
  const float* bo     = (const float*)d_in[10];
  const float* ln1s   = (const float*)d_in[11];
  const float* ln1b   = (const float*)d_in[12];
  const float* ln2s   = (const float*)d_in[13];
  const float* ln2b   = (const float*)d_in[14];
  const float* W1     = (const float*)d_in[15];
  const float* b1     = (const float*)d_in[16];
  const float* W2     = (const float*)d_in[17];
  const float* b2     = (const float*)d_in[18];
  const float* lnfs   = (const float*)d_in[19];
  const float* lnfb   = (const float*)d_in[20];
  const float* headb  = (const float*)d_in[21];
  (void)in_sizes; (void)n_in; (void)out_size; (void)ws_size;

  char* ws = (char*)d_ws;
  size_t off = 0;
  auto alloc = [&](size_t bytes) { void* p = ws + off; off += (bytes + 255) & ~(size_t)255; return p; };

  float* x     = (float*)alloc((size_t)CM * CD * 4);
  u16*   xn    = (u16*)  alloc((size_t)CM * CD * 2);
  u16*   qkvb  = (u16*)  alloc((size_t)CM * CQS * 2);
  u16*   ao    = (u16*)  alloc((size_t)CM * CD * 2);
  u16*   hb    = (u16*)  alloc((size_t)CM * CF * 2);
  u16*   Wqkvt = (u16*)  alloc((size_t)CQS * CD * 2);
  u16*   Wot   = (u16*)  alloc((size_t)CD * CD * 2);
  u16*   W1t   = (u16*)  alloc((size_t)CD * CF * 2);
  u16*   W2t   = (u16*)  alloc((size_t)CD * CF * 2);
  u16*   embC  = (u16*)  alloc((size_t)CV * CD * 2);   // bf16 copy of emb for head GEMM
  float* biasp = (float*)alloc((size_t)CL * CQS * 4);  // fused qkv bias

  embed_kernel<<<CM * CD / 256, 256, 0, stream>>>(X, emb, pos, x);
  convert_kernel<<<(CV * CD) / 256, 256, 0, stream>>>(emb, embC, CV * CD);
  biaspack_kernel<<<(CL * CQS) / 256, 256, 0, stream>>>(bq, bk, bv, biasp);

  const int QKV_TOT = CH * CD * CDH;        // 589824
  const int OO_TOT  = CD * CD;              // 589824
  const int FF_TOT  = CD * CF;              // 2359296

  for (int l = 0; l < CL; l++) {
    // weight repacks (coalesced transpose)
    trans_kernel<<<dim3(CD / 64, CDH / 32, CH), 256, 0, stream>>>(Wqkvt,                 Wq + (size_t)l * QKV_TOT, CD, CDH);
    trans_kernel<<<dim3(CD / 64, CDH / 32, CH), 256, 0, stream>>>(Wqkvt + 768 * 768,     Wk + (size_t)l * QKV_TOT, CD, CDH);
    trans_kernel<<<dim3(CD / 64, CDH / 32, CH), 256, 0, stream>>>(Wqkvt + 1536 * 768,    Wv + (size_t)l * QKV_TOT, CD, CDH);
    trans_kernel<<<dim3(CD / 64, CD / 32, 1),   256, 0, stream>>>(Wot, Wo + (size_t)l * OO_TOT, CD, CD);
    trans_kernel<<<dim3(CD / 64, CF / 32, 1),   256, 0, stream>>>(W1t, W1 + (size_t)l * FF_TOT, CD, CF);
    trans_kernel<<<dim3(CF / 64, CD / 32, 1),   256, 0, stream>>>(W2t, W2 + (size_t)l * FF_TOT, CF, CD);

    ln_kernel<<<CM, 256, 0, stream>>>(x, ln1s + l * CD, ln1b + l * CD, xn);

    // fused QKV GEMM: [2048 x 2304] = xn @ Wqkv^T
    gemm128_kernel<false, false, true><<<(CM / 128) * (CQS / 128), 256, 0, stream>>>(
        xn, Wqkvt, biasp + l * CQS, nullptr, qkvb, CM, CQS, CD);

    attn_mfma_kernel<<<dim3(CS / 64, CH, CB), 256, 0, stream>>>(qkvb, ao);

    gemm_kernel<true, false, false><<<dim3(CD / 64, CM / 64), 256, 0, stream>>>(ao, Wot, bo + l * CD, x, x, CM, CD, CD);

    ln_kernel<<<CM, 256, 0, stream>>>(x, ln2s + l * CD, ln2b + l * CD, xn);

    gemm128_kernel<false, true, true><<<(CM / 128) * (CF / 128), 256, 0, stream>>>(
        xn, W1t, b1 + l * CF, nullptr, hb, CM, CF, CD);

    gemm_kernel<true, false, false><<<dim3(CD / 64, CM / 64), 256, 0, stream>>>(hb, W2t, b2 + l * CD, x, x, CM, CD, CF);
  }

  ln_kernel<<<CM, 256, 0, stream>>>(x, lnfs, lnfb, xn);
  gemm128_kernel<false, false, false><<<(CM / 128) * (CV / 128), 256, 0, stream>>>(
      xn, embC, headb, nullptr, d_out, CM, CV, CD);
}

// Round 3
// 1578.871 us; speedup vs baseline: 3.2120x; 1.0487x over previous
//
#include <hip/hip_runtime.h>
#include <cstdint>
#include <cstddef>

// ---------- constants ----------
#define CL 6
#define CH 12
#define CD 768
#define CDH 64
#define CF 3072
#define CV 32000
#define CS 1024
#define CB 2
#define CM (CB*CS)   // 2048 token rows
#define CQS 2304     // fused qkv row stride

typedef unsigned short u16;
typedef __bf16 bf16x8 __attribute__((ext_vector_type(8)));
typedef float f32x4 __attribute__((ext_vector_type(4)));

__device__ __forceinline__ float bf2f(u16 u) {
  union { unsigned int i; float f; } c; c.i = ((unsigned int)u) << 16; return c.f;
}
__device__ __forceinline__ u16 f2bf(float f) {
  union { float f; unsigned int i; } c; c.f = f;
  unsigned int lsb = (c.i >> 16) & 1u;
  c.i += 0x7fffu + lsb;            // round-to-nearest-even
  return (u16)(c.i >> 16);
}

// async global->LDS, 16B per lane; LDS dest = wave-uniform base + lane*16
__device__ __forceinline__ void gload16(const u16* g, u16* l) {
  __builtin_amdgcn_global_load_lds(
      (const __attribute__((address_space(1))) void*)g,
      (__attribute__((address_space(3))) void*)l, 16, 0, 0);
}

// ---------- fp32 -> bf16 convert (for head weight emb) ----------
__global__ __launch_bounds__(256) void convert_kernel(
    const float* __restrict__ src, u16* __restrict__ dst, int total)
{
  int idx = blockIdx.x * 256 + threadIdx.x;
  if (idx < total) dst[idx] = f2bf(src[idx]);
}

// ---------- embedding: x[m,d] = emb[X[m],d] + pos[s,d] (fp32 in/out) ----------
__global__ __launch_bounds__(256) void embed_kernel(
    const int* __restrict__ X, const float* __restrict__ emb,
    const float* __restrict__ pos, float* __restrict__ x)
{
  int idx = blockIdx.x * 256 + threadIdx.x;      // grid covers exactly CM*CD
  int m = idx / CD, d = idx - m * CD;
  int s = m & (CS - 1);
  x[idx] = emb[(size_t)X[m] * CD + d] + pos[s * CD + d];
}

// ---------- layernorm (fp32 in, bf16 out), one block per row, one pass ----------
// 256 threads x 3 elems; fused sum+sumsq; wave shuffle reduce + 4-wave combine.
__global__ __launch_bounds__(256) void ln_kernel(
    const float* __restrict__ x, const float* __restrict__ gs,
    const float* __restrict__ gb, u16* __restrict__ out)
{
  __shared__ float rs[4], rss[4];
  int row = blockIdx.x, tid = threadIdx.x;
  const float* xr = x + (size_t)row * CD;
  float a0 = xr[tid], a1 = xr[tid + 256], a2 = xr[tid + 512];
  float s = a0 + a1 + a2;
  float ss = a0 * a0 + a1 * a1 + a2 * a2;
#pragma unroll
  for (int sh = 32; sh > 0; sh >>= 1) {
    s  += __shfl_xor(s, sh, 64);
    ss += __shfl_xor(ss, sh, 64);
  }
  int w = tid >> 6;
  if ((tid & 63) == 0) { rs[w] = s; rss[w] = ss; }
  __syncthreads();
  s  = rs[0] + rs[1] + rs[2] + rs[3];
  ss = rss[0] + rss[1] + rss[2] + rss[3];
  float mu = s * (1.f / CD);
  float inv = rsqrtf(ss * (1.f / CD) - mu * mu + 1e-5f);
  u16* orow = out + (size_t)row * CD;
  orow[tid]       = f2bf((a0 - mu) * inv * gs[tid]       + gb[tid]);
  orow[tid + 256] = f2bf((a1 - mu) * inv * gs[tid + 256] + gb[tid + 256]);
  orow[tid + 512] = f2bf((a2 - mu) * inv * gs[tid + 512] + gb[tid + 512]);
}

// ---------- coalesced transpose repack: per z-batch dst[c][r] = bf16(src[r][c]) ----
// src batch offset = bz*R*C (weights contiguous); dst offset =
// (bz/PB)*dstL + (bz%PB)*R*C  (PB sub-blocks per layer, layer stride dstL).
__global__ __launch_bounds__(256) void trans_kernel(
    u16* __restrict__ dst, const float* __restrict__ src, int R, int C,
    int PB, long dstL)
{
  __shared__ float st[32][65];   // st[c][r]
  int r0 = blockIdx.x * 64, c0 = blockIdx.y * 32, bz = blockIdx.z;
  const float* s = src + (size_t)bz * R * C;
  u16* d = dst + (size_t)(bz / PB) * dstL + (size_t)(bz % PB) * R * C;
  int tx = threadIdx.x & 31, ty = threadIdx.x >> 5;
#pragma unroll
  for (int i = 0; i < 8; i++) {
    int r = ty + 8 * i;
    st[tx][r] = s[(size_t)(r0 + r) * C + c0 + tx];
  }
  __syncthreads();
  int j = threadIdx.x & 15, cbase = threadIdx.x >> 4;
#pragma unroll
  for (int i = 0; i < 2; i++) {
    int c = cbase + 16 * i;
    uint2 pk;
    u16* p = (u16*)&pk;
    p[0] = f2bf(st[c][4 * j + 0]);
    p[1] = f2bf(st[c][4 * j + 1]);
    p[2] = f2bf(st[c][4 * j + 2]);
    p[3] = f2bf(st[c][4 * j + 3]);
    *(uint2*)&d[(size_t)(c0 + c) * R + r0 + 4 * j] = pk;
  }
}

// ---------- pack per-layer qkv bias: dst[l][0:768|768:1536|1536:2304] ----------
__global__ __launch_bounds__(256) void biaspack_kernel(
    const float* __restrict__ bq, const float* __restrict__ bk,
    const float* __restrict__ bv, float* __restrict__ dst)
{
  int idx = blockIdx.x * 256 + threadIdx.x;   // grid covers CL*2304 exactly
  int l = idx / CQS, c = idx - l * CQS;
  float val;
  if (c < 768)       val = bq[l * 768 + c];
  else if (c < 1536) val = bk[l * 768 + c - 768];
  else               val = bv[l * 768 + c - 1536];
  dst[idx] = val;
}

// ---------- MFMA GEMM 64x64, BK=64, global_load_lds staging (N=768 GEMMs) -------
template<bool RES, bool RELU, bool OUTBF>
__global__ __launch_bounds__(256) void gemm64v2_kernel(
    const u16* __restrict__ A, const u16* __restrict__ Bt,
    const float* __restrict__ bias, const float* __restrict__ res,
    void* __restrict__ outp, int M, int N, int K)
{
  __shared__ __align__(16) u16 As[64 * 64];
  __shared__ __align__(16) u16 Bs[64 * 64];
  int tid = threadIdx.x;
  int m0 = blockIdx.y * 64, n0 = blockIdx.x * 64;
  int wv = tid >> 6, ln = tid & 63;
  int quad = ln >> 4, l16 = ln & 15;
  int wm = (wv >> 1) * 32, wn = (wv & 1) * 32;

  // staging: chunk = it*256 + wv*64 + ln -> row = it*32 + wv*8 + (ln>>3), col8=(ln&7)*8
  int srow = wv * 8 + (ln >> 3);
  int scol = (ln & 7) * 8;
  const u16* gA = A  + (size_t)(m0 + srow) * K + scol;
  const u16* gB = Bt + (size_t)(n0 + srow) * K + scol;

  f32x4 acc[2][2];
  acc[0][0] = f32x4{0,0,0,0}; acc[0][1] = f32x4{0,0,0,0};
  acc[1][0] = f32x4{0,0,0,0}; acc[1][1] = f32x4{0,0,0,0};

  for (int kt = 0; kt < K; kt += 64) {
    __syncthreads();
#pragma unroll
    for (int it = 0; it < 2; it++) {
      gload16(gA + (size_t)it * 32 * K + kt, As + it * 2048 + wv * 512);
      gload16(gB + (size_t)it * 32 * K + kt, Bs + it * 2048 + wv * 512);
    }
    __syncthreads();
#pragma unroll
    for (int h = 0; h < 2; h++) {
      bf16x8 af[2], bf[2];
#pragma unroll
      for (int i = 0; i < 2; i++) {
        af[i] = *reinterpret_cast<const bf16x8*>(&As[(wm + i * 16 + l16) * 64 + h * 32 + quad * 8]);
        bf[i] = *reinterpret_cast<const bf16x8*>(&Bs[(wn + i * 16 + l16) * 64 + h * 32 + quad * 8]);
      }
#pragma unroll
      for (int i = 0; i < 2; i++)
#pragma unroll
        for (int j = 0; j < 2; j++)
          acc[i][j] = __builtin_amdgcn_mfma_f32_16x16x32_bf16(af[i], bf[j], acc[i][j], 0, 0, 0);
    }
  }

#pragma unroll
  for (int i = 0; i < 2; i++) {
    int gmb = m0 + wm + i * 16 + quad * 4;
#pragma unroll
    for (int j = 0; j < 2; j++) {
      int gn = n0 + wn + j * 16 + l16;
      float bsv = bias[gn];
#pragma unroll
      for (int rr = 0; rr < 4; rr++) {
        float val = acc[i][j][rr] + bsv;
        if (RELU) val = fmaxf(val, 0.f);
        size_t o = (size_t)(gmb + rr) * N + gn;
        if (RES) val += res[o];
        if (OUTBF) ((u16*)outp)[o] = f2bf(val);
        else       ((float*)outp)[o] = val;
      }
    }
  }
}

// ---------- MFMA GEMM 128x128, BK=64, global_load_lds staging ----------
// 4 waves, each a 64x64 quadrant (4x4 16x16x32 fragments); fragments loaded
// per-32-half so live VGPR stays at the BK=32 level. Bijective XCD chunking,
// bn-major inside chunk (B panel streams once device-wide; A stays L2-hot).
template<bool RES, bool RELU, bool OUTBF>
__global__ __launch_bounds__(256) void gemm128_kernel(
    const u16* __restrict__ A, const u16* __restrict__ Bt,
    const float* __restrict__ bias, const float* __restrict__ res,
    void* __restrict__ outp, int M, int N, int K)
{
  __shared__ __align__(16) u16 As[128 * 64];
  __shared__ __align__(16) u16 Bs[128 * 64];
  int tid = threadIdx.x;
  int nbm = M >> 7, nbn = N >> 7, nwg = nbm * nbn;
  int orig = blockIdx.x;
  int q8 = nwg >> 3, r8 = nwg & 7;
  int xcd = orig & 7;
  int t = ((xcd < r8) ? xcd * (q8 + 1) : r8 * (q8 + 1) + (xcd - r8) * q8) + (orig >> 3);
  int bm = t % nbm, bn = t / nbm;        // bn-major within chunk
  int m0 = bm << 7, n0 = bn << 7;

  int wv = tid >> 6, ln = tid & 63;
  int quad = ln >> 4, l16 = ln & 15;
  int wr = wv >> 1, wc = wv & 1;

  // staging: chunk = it*256 + wv*64 + ln -> row = it*32 + wv*8 + (ln>>3), col8=(ln&7)*8
  int srow = wv * 8 + (ln >> 3);
  int scol = (ln & 7) * 8;
  const u16* gA = A  + (size_t)(m0 + srow) * K + scol;
  const u16* gB = Bt + (size_t)(n0 + srow) * K + scol;

  f32x4 acc[4][4];
#pragma unroll
  for (int i = 0; i < 4; i++)
#pragma unroll
    for (int j = 0; j < 4; j++) acc[i][j] = f32x4{0.f, 0.f, 0.f, 0.f};

  for (int kt = 0; kt < K; kt += 64) {
    __syncthreads();                  // prev iter's ds_reads done before overwrite
#pragma unroll
    for (int it = 0; it < 4; it++) {
      gload16(gA + (size_t)it * 32 * K + kt, As + it * 2048 + wv * 512);
      gload16(gB + (size_t)it * 32 * K + kt, Bs + it * 2048 + wv * 512);
    }
    __syncthreads();                  // implies vmcnt(0): staged data visible
#pragma unroll
    for (int h = 0; h < 2; h++) {
      bf16x8 af[4], bf[4];
#pragma unroll
      for (int i = 0; i < 4; i++)
        af[i] = *reinterpret_cast<const bf16x8*>(&As[(wr * 64 + i * 16 + l16) * 64 + h * 32 + quad * 8]);
#pragma unroll
      for (int j = 0; j < 4; j++)
        bf[j] = *reinterpret_cast<const bf16x8*>(&Bs[(wc * 64 + j * 16 + l16) * 64 + h * 32 + quad * 8]);
#pragma unroll
      for (int i = 0; i < 4; i++)
#pragma unroll
        for (int j = 0; j < 4; j++)
          acc[i][j] = __builtin_amdgcn_mfma_f32_16x16x32_bf16(af[i], bf[j], acc[i][j], 0, 0, 0);
    }
  }

#pragma unroll
  for (int i = 0; i < 4; i++) {
    int gm = m0 + wr * 64 + i * 16 + quad * 4;
#pragma unroll
    for (int j = 0; j < 4; j++) {
      int gn = n0 + wc * 64 + j * 16 + l16;
      float bsv = bias[gn];
#pragma unroll
      for (int rr = 0; rr < 4; rr++) {
        float val = acc[i][j][rr] + bsv;
        if (RELU) val = fmaxf(val, 0.f);
        size_t oo = (size_t)(gm + rr) * N + gn;
        if (RES) val += res[oo];
        if (OUTBF) ((u16*)outp)[oo] = f2bf(val);
        else       ((float*)outp)[oo] = val;
      }
    }
  }
}

// ---------- MFMA flash attention (reads fused qkv buffer, stride 2304) ----------
__global__ __launch_bounds__(256) void attn_mfma_kernel(
    const u16* __restrict__ qkv, u16* __restrict__ o)
{
  __shared__ __align__(16) u16 Ks[64 * 64];        // K tile  [t][d] swizzled
  __shared__ __align__(16) u16 Vt[64 * 64];        // V tile transposed [d][t] swizzled
  __shared__ __align__(16) u16 Ps[4 * 16 * 64];    // per-wave P [q][t] swizzled

  int tid = threadIdx.x;
  int qb = (CS / 64 - 1) - blockIdx.x;             // reversed: heavy causal blocks first
  int h = blockIdx.y, b = blockIdx.z;
  int wid = tid >> 6, lane = tid & 63, quad = lane >> 4, l16 = lane & 15;
  int q0 = qb * 64;
  size_t bh = (size_t)b * CS * CQS + h * CDH;      // fused layout [(b*S+s)*2304 + seg + h*64 + d]

  // Q A-fragments straight from global (one-time)
  bf16x8 aq[2];
  {
    const u16* qrow = qkv + bh + (size_t)(q0 + wid * 16 + l16) * CQS;
#pragma unroll
    for (int ks = 0; ks < 2; ks++) {
      uint4 t = *(const uint4*)(qrow + ks * 32 + quad * 8);
      aq[ks] = *reinterpret_cast<bf16x8*>(&t);
    }
  }

  f32x4 oacc[4];
  float mrow[4], lrow[4];
#pragma unroll
  for (int j = 0; j < 4; j++) oacc[j] = f32x4{0.f, 0.f, 0.f, 0.f};
#pragma unroll
  for (int r = 0; r < 4; r++) { mrow[r] = -1e30f; lrow[r] = 0.f; }

  int srow = tid >> 3, schunk = tid & 7;       // K staging: 32 rows/iter x 8 chunks
  int vrow = tid >> 2, vseg = (tid & 3) * 16;  // V staging: row t, 16 d each

  for (int t0 = 0; t0 <= q0; t0 += 64) {
    __syncthreads();   // previous tile's LDS reads done
    // ---- stage K tile (vectorized, swizzled) ----
#pragma unroll
    for (int it = 0; it < 2; it++) {
      int row = srow + it * 32;
      uint4 kv4 = *(const uint4*)(qkv + bh + 768 + (size_t)(t0 + row) * CQS + schunk * 8);
      *(uint4*)&Ks[row * 64 + ((schunk ^ (row & 7)) * 8)] = kv4;
    }
    // ---- stage V transposed (scalar writes, swizzled) ----
    {
      const u16* vr = qkv + bh + 1536 + (size_t)(t0 + vrow) * CQS + vseg;
      uint4 a0 = *(const uint4*)(vr);
      uint4 a1 = *(const uint4*)(vr + 8);
      int c = vrow >> 3, w7 = vrow & 7;
#pragma unroll
      for (int i = 0; i < 16; i++) {
        int d = vseg + i;
        u16 val = (i < 8) ? ((const u16*)&a0)[i] : ((const u16*)&a1)[i - 8];
        Vt[d * 64 + (((c ^ (d & 7)) * 8) | w7)] = val;
      }
    }
    __syncthreads();   // staging complete

    // ---- S = Q K^T (per wave: 16q x 64t) ----
    f32x4 sacc[4];
#pragma unroll
    for (int j = 0; j < 4; j++) sacc[j] = f32x4{0.f, 0.f, 0.f, 0.f};
#pragma unroll
    for (int j = 0; j < 4; j++) {
      int row = j * 16 + l16;
#pragma unroll
      for (int ks = 0; ks < 2; ks++) {
        bf16x8 bk = *reinterpret_cast<const bf16x8*>(
            &Ks[row * 64 + ((((ks * 4 + quad) ^ (row & 7)) * 8))]);
        sacc[j] = __builtin_amdgcn_mfma_f32_16x16x32_bf16(aq[ks], bk, sacc[j], 0, 0, 0);
      }
    }

    // ---- scale + causal mask ----
    int qg0 = q0 + wid * 16 + quad * 4;   // q_glob for r=0
#pragma unroll
    for (int j = 0; j < 4; j++) {
      int tg = t0 + j * 16 + l16;
#pragma unroll
      for (int r = 0; r < 4; r++) {
        float s = sacc[j][r] * 0.125f;     // 1/sqrt(64)
        sacc[j][r] = (tg <= qg0 + r) ? s : -1e30f;
      }
    }

    // ---- online softmax ----
#pragma unroll
    for (int r = 0; r < 4; r++) {
      float m = fmaxf(fmaxf(sacc[0][r], sacc[1][r]), fmaxf(sacc[2][r], sacc[3][r]));
#pragma unroll
      for (int sh = 1; sh < 16; sh <<= 1) m = fmaxf(m, __shfl_xor(m, sh, 64));
      float mnew = fmaxf(mrow[r], m);
      float scal = __expf(mrow[r] - mnew);
      mrow[r] = mnew;
      lrow[r] *= scal;
#pragma unroll
      for (int j = 0; j < 4; j++) oacc[j][r] *= scal;
      float sum = 0.f;
#pragma unroll
      for (int j = 0; j < 4; j++) {
        float p = __expf(sacc[j][r] - mnew);
        sacc[j][r] = p;
        sum += p;
      }
#pragma unroll
      for (int sh = 1; sh < 16; sh <<= 1) sum += __shfl_xor(sum, sh, 64);
      lrow[r] += sum;
    }

    // ---- P -> LDS (bf16, per-wave region, swizzled) ----
    u16* Pw = Ps + wid * 1024;
#pragma unroll
    for (int j = 0; j < 4; j++) {
      int c = (l16 >> 3) + 2 * j;
#pragma unroll
      for (int r = 0; r < 4; r++) {
        int row = quad * 4 + r;
        Pw[row * 64 + (((c ^ (row & 7)) * 8) | (l16 & 7))] = f2bf(sacc[j][r]);
      }
    }

    // ---- O += P V ----
    bf16x8 ap[2];
#pragma unroll
    for (int ks = 0; ks < 2; ks++)
      ap[ks] = *reinterpret_cast<const bf16x8*>(
          &Pw[l16 * 64 + ((((ks * 4 + quad) ^ (l16 & 7)) * 8))]);
#pragma unroll
    for (int j = 0; j < 4; j++) {
      int row = j * 16 + l16;
#pragma unroll
      for (int ks = 0; ks < 2; ks++) {
        bf16x8 bv = *reinterpret_cast<const bf16x8*>(
            &Vt[row * 64 + ((((ks * 4 + quad) ^ (row & 7)) * 8))]);
        oacc[j] = __builtin_amdgcn_mfma_f32_16x16x32_bf16(ap[ks], bv, oacc[j], 0, 0, 0);
      }
    }
  }

  // ---- epilogue: O / l -> bf16 (output stride CD) ----
#pragma unroll
  for (int r = 0; r < 4; r++) {
    float inv = 1.f / lrow[r];
    int qg = q0 + wid * 16 + quad * 4 + r;
    u16* orow = o + (size_t)b * CS * CD + h * CDH + (size_t)qg * CD;
#pragma unroll
    for (int j = 0; j < 4; j++)
      orow[j * 16 + l16] = f2bf(oacc[j][r] * inv);
  }
}

// ---------- launcher ----------
extern "C" void kernel_launch(void* const* d_in, const int* in_sizes, int n_in,
                              void* d_out, int out_size, void* d_ws, size_t ws_size,
                              hipStream_t stream) {
  const int*   X      = (const int*)d_in[0];
  const float* emb    = (const float*)d_in[1];
  const float* pos    = (const float*)d_in[2];
  const float* Wq     = (const float*)d_in[3];
  const float* bq     = (const float*)d_in[4];
  const float* Wk     = (const float*)d_in[5];
  const float* bk     = (const float*)d_in[6];
  const float* Wv     = (const float*)d_in[7];
  const float* bv     = (const float*)d_in[8];
  const float* Wo     = (const float*)d_in[9];
  const float* bo     = (const float*)d_in[10];
  const float* ln1s   = (const float*)d_in[11];
  const float* ln1b   = (const float*)d_in[12];
  const float* ln2s   = (const float*)d_in[13];
  const float* ln2b   = (const float*)d_in[14];
  const float* W1     = (const float*)d_in[15];
  const float* b1     = (const float*)d_in[16];
  const float* W2     = (const float*)d_in[17];
  const float* b2     = (const float*)d_in[18];
  const float* lnfs   = (const float*)d_in[19];
  const float* lnfb   = (const float*)d_in[20];
  const float* headb  = (const float*)d_in[21];
  (void)in_sizes; (void)n_in; (void)out_size;

  char* ws = (char*)d_ws;
  size_t off = 0;
  auto alloc = [&](size_t bytes) { void* p = ws + off; off += (bytes + 255) & ~(size_t)255; return p; };

  float* x     = (float*)alloc((size_t)CM * CD * 4);
  u16*   xn    = (u16*)  alloc((size_t)CM * CD * 2);
  u16*   qkvb  = (u16*)  alloc((size_t)CM * CQS * 2);
  u16*   ao    = (u16*)  alloc((size_t)CM * CD * 2);
  u16*   hb    = (u16*)  alloc((size_t)CM * CF * 2);
  u16*   embC  = (u16*)  alloc((size_t)CV * CD * 2);   // bf16 copy of emb for head GEMM
  float* biasp = (float*)alloc((size_t)CL * CQS * 4);  // fused qkv bias

  // weight buffers: all-layer (fused repack, 6 launches) if workspace allows,
  // else per-layer (repack inside loop).
  const size_t WQKV = (size_t)CQS * CD;   // u16 elems per layer
  const size_t WOO  = (size_t)CD * CD;
  const size_t WFF  = (size_t)CD * CF;
  size_t perLayerElems = WQKV + WOO + 2 * WFF;
  bool fused = (ws_size >= off + (size_t)CL * perLayerElems * 2 + 4096);
  int LW = fused ? CL : 1;
  u16* Wqkvt = (u16*)alloc((size_t)LW * WQKV * 2);
  u16* Wot   = (u16*)alloc((size_t)LW * WOO * 2);
  u16* W1t   = (u16*)alloc((size_t)LW * WFF * 2);
  u16* W2t   = (u16*)alloc((size_t)LW * WFF * 2);

  embed_kernel<<<CM * CD / 256, 256, 0, stream>>>(X, emb, pos, x);
  convert_kernel<<<(CV * CD) / 256, 256, 0, stream>>>(emb, embC, CV * CD);
  biaspack_kernel<<<(CL * CQS) / 256, 256, 0, stream>>>(bq, bk, bv, biasp);

  if (fused) {
    trans_kernel<<<dim3(CD / 64, CDH / 32, CL * CH), 256, 0, stream>>>(Wqkvt,              Wq, CD, CDH, CH, (long)WQKV);
    trans_kernel<<<dim3(CD / 64, CDH / 32, CL * CH), 256, 0, stream>>>(Wqkvt + 768 * 768,  Wk, CD, CDH, CH, (long)WQKV);
    trans_kernel<<<dim3(CD / 64, CDH / 32, CL * CH), 256, 0, stream>>>(Wqkvt + 1536 * 768, Wv, CD, CDH, CH, (long)WQKV);
    trans_kernel<<<dim3(CD / 64, CD / 32, CL), 256, 0, stream>>>(Wot, Wo, CD, CD, 1, (long)WOO);
    trans_kernel<<<dim3(CD / 64, CF / 32, CL), 256, 0, stream>>>(W1t, W1, CD, CF, 1, (long)WFF);
    trans_kernel<<<dim3(CF / 64, CD / 32, CL), 256, 0, stream>>>(W2t, W2, CF, CD, 1, (long)WFF);
  }

  const int QKV_TOT = CH * CD * CDH;        // 589824

  for (int l = 0; l < CL; l++) {
    if (!fused) {
      trans_kernel<<<dim3(CD / 64, CDH / 32, CH), 256, 0, stream>>>(Wqkvt,              Wq + (size_t)l * QKV_TOT, CD, CDH, CH, (long)WQKV);
      trans_kernel<<<dim3(CD / 64, CDH / 32, CH), 256, 0, stream>>>(Wqkvt + 768 * 768,  Wk + (size_t)l * QKV_TOT, CD, CDH, CH, (long)WQKV);
      trans_kernel<<<dim3(CD / 64, CDH / 32, CH), 256, 0, stream>>>(Wqkvt + 1536 * 768, Wv + (size_t)l * QKV_TOT, CD, CDH, CH, (long)WQKV);
      trans_kernel<<<dim3(CD / 64, CD / 32, 1), 256, 0, stream>>>(Wot, Wo + (size_t)l * WOO, CD, CD, 1, (long)WOO);
      trans_kernel<<<dim3(CD / 64, CF / 32, 1), 256, 0, stream>>>(W1t, W1 + (size_t)l * WFF, CD, CF, 1, (long)WFF);
      trans_kernel<<<dim3(CF / 64, CD / 32, 1), 256, 0, stream>>>(W2t, W2 + (size_t)l * WFF, CF, CD, 1, (long)WFF);
    }
    int lw = fused ? l : 0;
    const u16* wqkv = Wqkvt + (size_t)lw * WQKV;
    const u16* wot  = Wot   + (size_t)lw * WOO;
    const u16* w1t  = W1t   + (size_t)lw * WFF;
    const u16* w2t  = W2t   + (size_t)lw * WFF;

    ln_kernel<<<CM, 256, 0, stream>>>(x, ln1s + l * CD, ln1b + l * CD, xn);

    gemm128_kernel<false, false, true><<<(CM / 128) * (CQS / 128), 256, 0, stream>>>(
        xn, wqkv, biasp + l * CQS, nullptr, qkvb, CM, CQS, CD);

    attn_mfma_kernel<<<dim3(CS / 64, CH, CB), 256, 0, stream>>>(qkvb, ao);

    gemm64v2_kernel<true, false, false><<<dim3(CD / 64, CM / 64), 256, 0, stream>>>(
        ao, wot, bo + l * CD, x, x, CM, CD, CD);

    ln_kernel<<<CM, 256, 0, stream>>>(x, ln2s + l * CD, ln2b + l * CD, xn);

    gemm128_kernel<false, true, true><<<(CM / 128) * (CF / 128), 256, 0, stream>>>(
        xn, w1t, b1 + l * CF, nullptr, hb, CM, CF, CD);

    gemm64v2_kernel<true, false, false><<<dim3(CD / 64, CM / 64), 256, 0, stream>>>(
        hb, w2t, b2 + l * CD, x, x, CM, CD, CF);
  }

  ln_kernel<<<CM, 256, 0, stream>>>(x, lnfs, lnfb, xn);
  gemm128_kernel<false, false, false><<<(CM / 128) * (CV / 128), 256, 0, stream>>>(
      xn, embC, headb, nullptr, d_out, CM, CV, CD);
}

// Round 4
// 1569.988 us; speedup vs baseline: 3.2302x; 1.0057x over previous
//
#include <hip/hip_runtime.h>
#include <cstdint>
#include <cstddef>

// ---------- constants ----------
#define CL 6
#define CH 12
#define CD 768
#define CDH 64
#define CF 3072
#define CV 32000
#define CS 1024
#define CB 2
#define CM (CB*CS)   // 2048 token rows
#define CQS 2304     // fused qkv row stride

typedef unsigned short u16;
typedef __bf16 bf16x8 __attribute__((ext_vector_type(8)));
typedef float f32x4 __attribute__((ext_vector_type(4)));

__device__ __forceinline__ float bf2f(u16 u) {
  union { unsigned int i; float f; } c; c.i = ((unsigned int)u) << 16; return c.f;
}
__device__ __forceinline__ u16 f2bf(float f) {
  union { float f; unsigned int i; } c; c.f = f;
  unsigned int lsb = (c.i >> 16) & 1u;
  c.i += 0x7fffu + lsb;            // round-to-nearest-even
  return (u16)(c.i >> 16);
}

// async global->LDS, 16B per lane; LDS dest = wave-uniform base + lane*16
__device__ __forceinline__ void gload16(const u16* g, u16* l) {
  __builtin_amdgcn_global_load_lds(
      (const __attribute__((address_space(1))) void*)g,
      (__attribute__((address_space(3))) void*)l, 16, 0, 0);
}

// ---------- fp32 -> bf16 convert (for head weight emb) ----------
__global__ __launch_bounds__(256) void convert_kernel(
    const float* __restrict__ src, u16* __restrict__ dst, int total)
{
  int idx = blockIdx.x * 256 + threadIdx.x;
  if (idx < total) dst[idx] = f2bf(src[idx]);
}

// ---------- embedding: x[m,d] = emb[X[m],d] + pos[s,d] (fp32 in/out) ----------
__global__ __launch_bounds__(256) void embed_kernel(
    const int* __restrict__ X, const float* __restrict__ emb,
    const float* __restrict__ pos, float* __restrict__ x)
{
  int idx = blockIdx.x * 256 + threadIdx.x;      // grid covers exactly CM*CD
  int m = idx / CD, d = idx - m * CD;
  int s = m & (CS - 1);
  x[idx] = emb[(size_t)X[m] * CD + d] + pos[s * CD + d];
}

// ---------- layernorm (fp32 in, bf16 out), one block per row, one pass ----------
__global__ __launch_bounds__(256) void ln_kernel(
    const float* __restrict__ x, const float* __restrict__ gs,
    const float* __restrict__ gb, u16* __restrict__ out)
{
  __shared__ float rs[4], rss[4];
  int row = blockIdx.x, tid = threadIdx.x;
  const float* xr = x + (size_t)row * CD;
  float a0 = xr[tid], a1 = xr[tid + 256], a2 = xr[tid + 512];
  float s = a0 + a1 + a2;
  float ss = a0 * a0 + a1 * a1 + a2 * a2;
#pragma unroll
  for (int sh = 32; sh > 0; sh >>= 1) {
    s  += __shfl_xor(s, sh, 64);
    ss += __shfl_xor(ss, sh, 64);
  }
  int w = tid >> 6;
  if ((tid & 63) == 0) { rs[w] = s; rss[w] = ss; }
  __syncthreads();
  s  = rs[0] + rs[1] + rs[2] + rs[3];
  ss = rss[0] + rss[1] + rss[2] + rss[3];
  float mu = s * (1.f / CD);
  float inv = rsqrtf(ss * (1.f / CD) - mu * mu + 1e-5f);
  u16* orow = out + (size_t)row * CD;
  orow[tid]       = f2bf((a0 - mu) * inv * gs[tid]       + gb[tid]);
  orow[tid + 256] = f2bf((a1 - mu) * inv * gs[tid + 256] + gb[tid + 256]);
  orow[tid + 512] = f2bf((a2 - mu) * inv * gs[tid + 512] + gb[tid + 512]);
}

// ---------- coalesced transpose repack: per z-batch dst[c][r] = bf16(src[r][c]) ----
__global__ __launch_bounds__(256) void trans_kernel(
    u16* __restrict__ dst, const float* __restrict__ src, int R, int C,
    int PB, long dstL)
{
  __shared__ float st[32][65];   // st[c][r]
  int r0 = blockIdx.x * 64, c0 = blockIdx.y * 32, bz = blockIdx.z;
  const float* s = src + (size_t)bz * R * C;
  u16* d = dst + (size_t)(bz / PB) * dstL + (size_t)(bz % PB) * R * C;
  int tx = threadIdx.x & 31, ty = threadIdx.x >> 5;
#pragma unroll
  for (int i = 0; i < 8; i++) {
    int r = ty + 8 * i;
    st[tx][r] = s[(size_t)(r0 + r) * C + c0 + tx];
  }
  __syncthreads();
  int j = threadIdx.x & 15, cbase = threadIdx.x >> 4;
#pragma unroll
  for (int i = 0; i < 2; i++) {
    int c = cbase + 16 * i;
    uint2 pk;
    u16* p = (u16*)&pk;
    p[0] = f2bf(st[c][4 * j + 0]);
    p[1] = f2bf(st[c][4 * j + 1]);
    p[2] = f2bf(st[c][4 * j + 2]);
    p[3] = f2bf(st[c][4 * j + 3]);
    *(uint2*)&d[(size_t)(c0 + c) * R + r0 + 4 * j] = pk;
  }
}

// ---------- pack per-layer qkv bias ----------
__global__ __launch_bounds__(256) void biaspack_kernel(
    const float* __restrict__ bq, const float* __restrict__ bk,
    const float* __restrict__ bv, float* __restrict__ dst)
{
  int idx = blockIdx.x * 256 + threadIdx.x;   // grid covers CL*2304 exactly
  int l = idx / CQS, c = idx - l * CQS;
  float val;
  if (c < 768)       val = bq[l * 768 + c];
  else if (c < 1536) val = bk[l * 768 + c - 768];
  else               val = bv[l * 768 + c - 1536];
  dst[idx] = val;
}

// ---------- MFMA GEMM 64x64, BK=32, global_load_lds staging (N=768 GEMMs) ------
template<bool RES, bool RELU, bool OUTBF>
__global__ __launch_bounds__(256) void gemm64v3_kernel(
    const u16* __restrict__ A, const u16* __restrict__ Bt,
    const float* __restrict__ bias, const float* __restrict__ res,
    void* __restrict__ outp, int M, int N, int K)
{
  __shared__ __align__(16) u16 As[64 * 32];
  __shared__ __align__(16) u16 Bs[64 * 32];
  int tid = threadIdx.x;
  int m0 = blockIdx.y * 64, n0 = blockIdx.x * 64;
  int wv = tid >> 6, ln = tid & 63;
  int quad = ln >> 4, l16 = ln & 15;
  int wm = (wv >> 1) * 32, wn = (wv & 1) * 32;
  // staging: chunk = tid -> row = tid>>2, col8 = (tid&3)*8; one gload per matrix
  int srow = tid >> 2, scol = (tid & 3) * 8;
  const u16* gA = A  + (size_t)(m0 + srow) * K + scol;
  const u16* gB = Bt + (size_t)(n0 + srow) * K + scol;
  u16* lA = As + wv * 512;
  u16* lB = Bs + wv * 512;

  f32x4 acc[2][2];
  acc[0][0] = f32x4{0,0,0,0}; acc[0][1] = f32x4{0,0,0,0};
  acc[1][0] = f32x4{0,0,0,0}; acc[1][1] = f32x4{0,0,0,0};

  for (int kt = 0; kt < K; kt += 32) {
    __syncthreads();
    gload16(gA + kt, lA);
    gload16(gB + kt, lB);
    __syncthreads();
    bf16x8 af[2], bfr[2];
#pragma unroll
    for (int i = 0; i < 2; i++) {
      af[i]  = *reinterpret_cast<const bf16x8*>(&As[(wm + i * 16 + l16) * 32 + quad * 8]);
      bfr[i] = *reinterpret_cast<const bf16x8*>(&Bs[(wn + i * 16 + l16) * 32 + quad * 8]);
    }
#pragma unroll
    for (int i = 0; i < 2; i++)
#pragma unroll
      for (int j = 0; j < 2; j++)
        acc[i][j] = __builtin_amdgcn_mfma_f32_16x16x32_bf16(af[i], bfr[j], acc[i][j], 0, 0, 0);
  }

#pragma unroll
  for (int i = 0; i < 2; i++) {
    int gmb = m0 + wm + i * 16 + quad * 4;
#pragma unroll
    for (int j = 0; j < 2; j++) {
      int gn = n0 + wn + j * 16 + l16;
      float bsv = bias[gn];
#pragma unroll
      for (int rr = 0; rr < 4; rr++) {
        float val = acc[i][j][rr] + bsv;
        if (RELU) val = fmaxf(val, 0.f);
        size_t o = (size_t)(gmb + rr) * N + gn;
        if (RES) val += res[o];
        if (OUTBF) ((u16*)outp)[o] = f2bf(val);
        else       ((float*)outp)[o] = val;
      }
    }
  }
}

// ---------- MFMA GEMM 128x128, BK=32, global_load_lds staging (m97 structure) ----
// (harness-verified r2 form: 16 KB LDS, ~29% occupancy, 193 us head GEMM)
template<bool RES, bool RELU, bool OUTBF>
__global__ __launch_bounds__(256) void gemm128_kernel(
    const u16* __restrict__ A, const u16* __restrict__ Bt,
    const float* __restrict__ bias, const float* __restrict__ res,
    void* __restrict__ outp, int M, int N, int K)
{
  __shared__ __align__(16) u16 As[128 * 32];
  __shared__ __align__(16) u16 Bs[128 * 32];
  int tid = threadIdx.x;
  int nbm = M >> 7, nbn = N >> 7, nwg = nbm * nbn;
  int orig = blockIdx.x;
  int q8 = nwg >> 3, r8 = nwg & 7;
  int xcd = orig & 7;
  int t = ((xcd < r8) ? xcd * (q8 + 1) : r8 * (q8 + 1) + (xcd - r8) * q8) + (orig >> 3);
  int bm = t % nbm, bn = t / nbm;        // bn-major within chunk
  int m0 = bm << 7, n0 = bn << 7;

  int wv = tid >> 6, ln = tid & 63;
  int quad = ln >> 4, l16 = ln & 15;
  int wr = wv >> 1, wc = wv & 1;

  int srow = wv * 16 + (ln >> 2);
  int scol = (ln & 3) * 8;
  const u16* ga0 = A  + (size_t)(m0 + srow) * K + scol;
  const u16* ga1 = A  + (size_t)(m0 + srow + 64) * K + scol;
  const u16* gb0 = Bt + (size_t)(n0 + srow) * K + scol;
  const u16* gb1 = Bt + (size_t)(n0 + srow + 64) * K + scol;
  u16* lA0 = As + wv * 512;
  u16* lA1 = As + 2048 + wv * 512;
  u16* lB0 = Bs + wv * 512;
  u16* lB1 = Bs + 2048 + wv * 512;

  f32x4 acc[4][4];
#pragma unroll
  for (int i = 0; i < 4; i++)
#pragma unroll
    for (int j = 0; j < 4; j++) acc[i][j] = f32x4{0.f, 0.f, 0.f, 0.f};

  for (int kt = 0; kt < K; kt += 32) {
    __syncthreads();                  // prev iter's ds_reads done before overwrite
    gload16(ga0 + kt, lA0);
    gload16(ga1 + kt, lA1);
    gload16(gb0 + kt, lB0);
    gload16(gb1 + kt, lB1);
    __syncthreads();                  // implies vmcnt(0): staged data visible
    bf16x8 af[4], bf[4];
#pragma unroll
    for (int i = 0; i < 4; i++)
      af[i] = *reinterpret_cast<const bf16x8*>(&As[(wr * 64 + i * 16 + l16) * 32 + quad * 8]);
#pragma unroll
    for (int j = 0; j < 4; j++)
      bf[j] = *reinterpret_cast<const bf16x8*>(&Bs[(wc * 64 + j * 16 + l16) * 32 + quad * 8]);
#pragma unroll
    for (int i = 0; i < 4; i++)
#pragma unroll
      for (int j = 0; j < 4; j++)
        acc[i][j] = __builtin_amdgcn_mfma_f32_16x16x32_bf16(af[i], bf[j], acc[i][j], 0, 0, 0);
  }

#pragma unroll
  for (int i = 0; i < 4; i++) {
    int gm = m0 + wr * 64 + i * 16 + quad * 4;
#pragma unroll
    for (int j = 0; j < 4; j++) {
      int gn = n0 + wc * 64 + j * 16 + l16;
      float bsv = bias[gn];
#pragma unroll
      for (int rr = 0; rr < 4; rr++) {
        float val = acc[i][j][rr] + bsv;
        if (RELU) val = fmaxf(val, 0.f);
        size_t oo = (size_t)(gm + rr) * N + gn;
        if (RES) val += res[oo];
        if (OUTBF) ((u16*)outp)[oo] = f2bf(val);
        else       ((float*)outp)[oo] = val;
      }
    }
  }
}

// ---------- MFMA flash attention v2: double-buffered tiles, 1 barrier/tile ------
// K staged via global_load_lds with pre-swizzled per-lane SOURCE (linear LDS dest,
// swizzled read -- rule: both-sides-or-neither). V transposed in-register:
// uint2 reads issued BEFORE compute, ds_write_b64 landed AFTER (issue-early /
// write-late), so HBM latency hides under QK^T+softmax+PV of the current tile.
__global__ __launch_bounds__(256) void attn_mfma_kernel(
    const u16* __restrict__ qkv, u16* __restrict__ o)
{
  __shared__ __align__(16) u16 Ks[2][64 * 64];     // K tile  [t][d] swizzled
  __shared__ __align__(16) u16 Vt[2][64 * 64];     // V tile transposed [d][t] swizzled
  __shared__ __align__(16) u16 Ps[4 * 16 * 64];    // per-wave P [q][t] swizzled

  int tid = threadIdx.x;
  int qb = (CS / 64 - 1) - blockIdx.x;             // reversed: heavy causal blocks first
  int h = blockIdx.y, b = blockIdx.z;
  int wid = tid >> 6, lane = tid & 63, quad = lane >> 4, l16 = lane & 15;
  int q0 = qb * 64;
  size_t bh = (size_t)b * CS * CQS + h * CDH;      // fused layout [(b*S+s)*2304 + seg + h*64 + d]

  const u16* kbase = qkv + bh + 768;
  const u16* vbase = qkv + bh + 1536;

  // staging maps
  int t4 = (tid & 15) * 4, dg = (tid >> 4) * 4;    // V: 4 consecutive t rows x 4 d
  // K chunk c (16B): row = c>>3, linear col8 = c&7, source col8 = (c&7)^(row&7)

  // Q A-fragments straight from global (one-time)
  bf16x8 aq[2];
  {
    const u16* qrow = qkv + bh + (size_t)(q0 + wid * 16 + l16) * CQS;
#pragma unroll
    for (int ks = 0; ks < 2; ks++) {
      uint4 t = *(const uint4*)(qrow + ks * 32 + quad * 8);
      aq[ks] = *reinterpret_cast<bf16x8*>(&t);
    }
  }

  f32x4 oacc[4];
  float mrow[4], lrow[4];
#pragma unroll
  for (int j = 0; j < 4; j++) oacc[j] = f32x4{0.f, 0.f, 0.f, 0.f};
#pragma unroll
  for (int r = 0; r < 4; r++) { mrow[r] = -1e30f; lrow[r] = 0.f; }

  // ---- prologue: stage tile 0 into buf 0 ----
  {
#pragma unroll
    for (int it = 0; it < 2; it++) {
      int c = it * 256 + tid;
      int row = c >> 3, c8l = c & 7;
      gload16(kbase + (size_t)row * CQS + (((c8l ^ (row & 7)) * 8)),
              &Ks[0][(it * 256 + wid * 64) * 8]);
    }
    uint2 vr[4];
#pragma unroll
    for (int i = 0; i < 4; i++)
      vr[i] = *(const uint2*)(vbase + (size_t)(t4 + i) * CQS + dg);
#pragma unroll
    for (int j = 0; j < 4; j++) {
      int d = dg + j;
      uint2 pk;
      u16* p = (u16*)&pk;
      p[0] = ((const u16*)&vr[0])[j]; p[1] = ((const u16*)&vr[1])[j];
      p[2] = ((const u16*)&vr[2])[j]; p[3] = ((const u16*)&vr[3])[j];
      *(uint2*)&Vt[0][d * 64 + (((t4 >> 3) ^ (d & 7)) * 8) + (t4 & 4)] = pk;
    }
  }

  for (int t0 = 0; t0 <= q0; t0 += 64) {
    int cur = (t0 >> 6) & 1;
    __syncthreads();   // buf[cur] staged (vmcnt+lds drained); buf[cur^1] free
    bool hasnext = (t0 + 64 <= q0);
    uint2 vr[4];
    if (hasnext) {
      const u16* vb2 = vbase + (size_t)(t0 + 64) * CQS;
#pragma unroll
      for (int i = 0; i < 4; i++)
        vr[i] = *(const uint2*)(vb2 + (size_t)(t4 + i) * CQS + dg);
      const u16* kb2 = kbase + (size_t)(t0 + 64) * CQS;
#pragma unroll
      for (int it = 0; it < 2; it++) {
        int c = it * 256 + tid;
        int row = c >> 3, c8l = c & 7;
        gload16(kb2 + (size_t)row * CQS + (((c8l ^ (row & 7)) * 8)),
                &Ks[cur ^ 1][(it * 256 + wid * 64) * 8]);
      }
    }

    // ---- S = Q K^T (per wave: 16q x 64t) ----
    f32x4 sacc[4];
#pragma unroll
    for (int j = 0; j < 4; j++) sacc[j] = f32x4{0.f, 0.f, 0.f, 0.f};
#pragma unroll
    for (int j = 0; j < 4; j++) {
      int row = j * 16 + l16;
#pragma unroll
      for (int ks = 0; ks < 2; ks++) {
        bf16x8 bk = *reinterpret_cast<const bf16x8*>(
            &Ks[cur][row * 64 + ((((ks * 4 + quad) ^ (row & 7)) * 8))]);
        sacc[j] = __builtin_amdgcn_mfma_f32_16x16x32_bf16(aq[ks], bk, sacc[j], 0, 0, 0);
      }
    }

    // ---- scale + causal mask ----
    int qg0 = q0 + wid * 16 + quad * 4;   // q_glob for r=0
#pragma unroll
    for (int j = 0; j < 4; j++) {
      int tg = t0 + j * 16 + l16;
#pragma unroll
      for (int r = 0; r < 4; r++) {
        float s = sacc[j][r] * 0.125f;     // 1/sqrt(64)
        sacc[j][r] = (tg <= qg0 + r) ? s : -1e30f;
      }
    }

    // ---- online softmax ----
#pragma unroll
    for (int r = 0; r < 4; r++) {
      float m = fmaxf(fmaxf(sacc[0][r], sacc[1][r]), fmaxf(sacc[2][r], sacc[3][r]));
#pragma unroll
      for (int sh = 1; sh < 16; sh <<= 1) m = fmaxf(m, __shfl_xor(m, sh, 64));
      float mnew = fmaxf(mrow[r], m);
      float scal = __expf(mrow[r] - mnew);
      mrow[r] = mnew;
      lrow[r] *= scal;
#pragma unroll
      for (int j = 0; j < 4; j++) oacc[j][r] *= scal;
      float sum = 0.f;
#pragma unroll
      for (int j = 0; j < 4; j++) {
        float p = __expf(sacc[j][r] - mnew);
        sacc[j][r] = p;
        sum += p;
      }
#pragma unroll
      for (int sh = 1; sh < 16; sh <<= 1) sum += __shfl_xor(sum, sh, 64);
      lrow[r] += sum;
    }

    // ---- P -> LDS (bf16, per-wave region, swizzled; no barrier needed) ----
    u16* Pw = Ps + wid * 1024;
#pragma unroll
    for (int j = 0; j < 4; j++) {
      int c = (l16 >> 3) + 2 * j;
#pragma unroll
      for (int r = 0; r < 4; r++) {
        int row = quad * 4 + r;
        Pw[row * 64 + (((c ^ (row & 7)) * 8) | (l16 & 7))] = f2bf(sacc[j][r]);
      }
    }

    // ---- O += P V ----
    bf16x8 ap[2];
#pragma unroll
    for (int ks = 0; ks < 2; ks++)
      ap[ks] = *reinterpret_cast<const bf16x8*>(
          &Pw[l16 * 64 + ((((ks * 4 + quad) ^ (l16 & 7)) * 8))]);
#pragma unroll
    for (int j = 0; j < 4; j++) {
      int row = j * 16 + l16;
#pragma unroll
      for (int ks = 0; ks < 2; ks++) {
        bf16x8 bv = *reinterpret_cast<const bf16x8*>(
            &Vt[cur][row * 64 + ((((ks * 4 + quad) ^ (row & 7)) * 8))]);
        oacc[j] = __builtin_amdgcn_mfma_f32_16x16x32_bf16(ap[ks], bv, oacc[j], 0, 0, 0);
      }
    }

    // ---- V write-late into buf[cur^1] (completes before next top barrier) ----
    if (hasnext) {
#pragma unroll
      for (int j = 0; j < 4; j++) {
        int d = dg + j;
        uint2 pk;
        u16* p = (u16*)&pk;
        p[0] = ((const u16*)&vr[0])[j]; p[1] = ((const u16*)&vr[1])[j];
        p[2] = ((const u16*)&vr[2])[j]; p[3] = ((const u16*)&vr[3])[j];
        *(uint2*)&Vt[cur ^ 1][d * 64 + (((t4 >> 3) ^ (d & 7)) * 8) + (t4 & 4)] = pk;
      }
    }
  }

  // ---- epilogue: O / l -> bf16 (output stride CD) ----
#pragma unroll
  for (int r = 0; r < 4; r++) {
    float inv = 1.f / lrow[r];
    int qg = q0 + wid * 16 + quad * 4 + r;
    u16* orow = o + (size_t)b * CS * CD + h * CDH + (size_t)qg * CD;
#pragma unroll
    for (int j = 0; j < 4; j++)
      orow[j * 16 + l16] = f2bf(oacc[j][r] * inv);
  }
}

// ---------- launcher ----------
extern "C" void kernel_launch(void* const* d_in, const int* in_sizes, int n_in,
                              void* d_out, int out_size, void* d_ws, size_t ws_size,
                              hipStream_t stream) {
  const int*   X      = (const int*)d_in[0];
  const float* emb    = (const float*)d_in[1];
  const float* pos    = (const float*)d_in[2];
  const float* Wq     = (const float*)d_in[3];
  const float* bq     = (const float*)d_in[4];
  const float* Wk     = (const float*)d_in[5];
  const float* bk     = (const float*)d_in[6];
  const float* Wv     = (const float*)d_in[7];
  const float* bv     = (const float*)d_in[8];
  const float* Wo     = (const float*)d_in[9];
  const float* bo     = (const float*)d_in[10];
  const float* ln1s   = (const float*)d_in[11];
  const float* ln1b   = (const float*)d_in[12];
  const float* ln2s   = (const float*)d_in[13];
  const float* ln2b   = (const float*)d_in[14];
  const float* W1     = (const float*)d_in[15];
  const float* b1     = (const float*)d_in[16];
  const float* W2     = (const float*)d_in[17];
  const float* b2     = (const float*)d_in[18];
  const float* lnfs   = (const float*)d_in[19];
  const float* lnfb   = (const float*)d_in[20];
  const float* headb  = (const float*)d_in[21];
  (void)in_sizes; (void)n_in; (void)out_size;

  char* ws = (char*)d_ws;
  size_t off = 0;
  auto alloc = [&](size_t bytes) { void* p = ws + off; off += (bytes + 255) & ~(size_t)255; return p; };

  float* x     = (float*)alloc((size_t)CM * CD * 4);
  u16*   xn    = (u16*)  alloc((size_t)CM * CD * 2);
  u16*   qkvb  = (u16*)  alloc((size_t)CM * CQS * 2);
  u16*   ao    = (u16*)  alloc((size_t)CM * CD * 2);
  u16*   hb    = (u16*)  alloc((size_t)CM * CF * 2);
  u16*   embC  = (u16*)  alloc((size_t)CV * CD * 2);   // bf16 copy of emb for head GEMM
  float* biasp = (float*)alloc((size_t)CL * CQS * 4);  // fused qkv bias

  const size_t WQKV = (size_t)CQS * CD;   // u16 elems per layer
  const size_t WOO  = (size_t)CD * CD;
  const size_t WFF  = (size_t)CD * CF;
  size_t perLayerElems = WQKV + WOO + 2 * WFF;
  bool fused = (ws_size >= off + (size_t)CL * perLayerElems * 2 + 4096);
  int LW = fused ? CL : 1;
  u16* Wqkvt = (u16*)alloc((size_t)LW * WQKV * 2);
  u16* Wot   = (u16*)alloc((size_t)LW * WOO * 2);
  u16* W1t   = (u16*)alloc((size_t)LW * WFF * 2);
  u16* W2t   = (u16*)alloc((size_t)LW * WFF * 2);

  embed_kernel<<<CM * CD / 256, 256, 0, stream>>>(X, emb, pos, x);
  convert_kernel<<<(CV * CD) / 256, 256, 0, stream>>>(emb, embC, CV * CD);
  biaspack_kernel<<<(CL * CQS) / 256, 256, 0, stream>>>(bq, bk, bv, biasp);

  if (fused) {
    trans_kernel<<<dim3(CD / 64, CDH / 32, CL * CH), 256, 0, stream>>>(Wqkvt,              Wq, CD, CDH, CH, (long)WQKV);
    trans_kernel<<<dim3(CD / 64, CDH / 32, CL * CH), 256, 0, stream>>>(Wqkvt + 768 * 768,  Wk, CD, CDH, CH, (long)WQKV);
    trans_kernel<<<dim3(CD / 64, CDH / 32, CL * CH), 256, 0, stream>>>(Wqkvt + 1536 * 768, Wv, CD, CDH, CH, (long)WQKV);
    trans_kernel<<<dim3(CD / 64, CD / 32, CL), 256, 0, stream>>>(Wot, Wo, CD, CD, 1, (long)WOO);
    trans_kernel<<<dim3(CD / 64, CF / 32, CL), 256, 0, stream>>>(W1t, W1, CD, CF, 1, (long)WFF);
    trans_kernel<<<dim3(CF / 64, CD / 32, CL), 256, 0, stream>>>(W2t, W2, CF, CD, 1, (long)WFF);
  }

  const int QKV_TOT = CH * CD * CDH;        // 589824

  for (int l = 0; l < CL; l++) {
    if (!fused) {
      trans_kernel<<<dim3(CD / 64, CDH / 32, CH), 256, 0, stream>>>(Wqkvt,              Wq + (size_t)l * QKV_TOT, CD, CDH, CH, (long)WQKV);
      trans_kernel<<<dim3(CD / 64, CDH / 32, CH), 256, 0, stream>>>(Wqkvt + 768 * 768,  Wk + (size_t)l * QKV_TOT, CD, CDH, CH, (long)WQKV);
      trans_kernel<<<dim3(CD / 64, CDH / 32, CH), 256, 0, stream>>>(Wqkvt + 1536 * 768, Wv + (size_t)l * QKV_TOT, CD, CDH, CH, (long)WQKV);
      trans_kernel<<<dim3(CD / 64, CD / 32, 1), 256, 0, stream>>>(Wot, Wo + (size_t)l * WOO, CD, CD, 1, (long)WOO);
      trans_kernel<<<dim3(CD / 64, CF / 32, 1), 256, 0, stream>>>(W1t, W1 + (size_t)l * WFF, CD, CF, 1, (long)WFF);
      trans_kernel<<<dim3(CF / 64, CD / 32, 1), 256, 0, stream>>>(W2t, W2 + (size_t)l * WFF, CF, CD, 1, (long)WFF);
    }
    int lw = fused ? l : 0;
    const u16* wqkv = Wqkvt + (size_t)lw * WQKV;
    const u16* wot  = Wot   + (size_t)lw * WOO;
    const u16* w1t  = W1t   + (size_t)lw * WFF;
    const u16* w2t  = W2t   + (size_t)lw * WFF;

    ln_kernel<<<CM, 256, 0, stream>>>(x, ln1s + l * CD, ln1b + l * CD, xn);

    gemm128_kernel<false, false, true><<<(CM / 128) * (CQS / 128), 256, 0, stream>>>(
        xn, wqkv, biasp + l * CQS, nullptr, qkvb, CM, CQS, CD);

    attn_mfma_kernel<<<dim3(CS / 64, CH, CB), 256, 0, stream>>>(qkvb, ao);

    gemm64v3_kernel<true, false, false><<<dim3(CD / 64, CM / 64), 256, 0, stream>>>(
        ao, wot, bo + l * CD, x, x, CM, CD, CD);

    ln_kernel<<<CM, 256, 0, stream>>>(x, ln2s + l * CD, ln2b + l * CD, xn);

    gemm128_kernel<false, true, true><<<(CM / 128) * (CF / 128), 256, 0, stream>>>(
        xn, w1t, b1 + l * CF, nullptr, hb, CM, CF, CD);

    gemm64v3_kernel<true, false, false><<<dim3(CD / 64, CM / 64), 256, 0, stream>>>(
        hb, w2t, b2 + l * CD, x, x, CM, CD, CF);
  }

  ln_kernel<<<CM, 256, 0, stream>>>(x, lnfs, lnfb, xn);
  gemm128_kernel<false, false, false><<<(CM / 128) * (CV / 128), 256, 0, stream>>>(
      xn, embC, headb, nullptr, d_out, CM, CV, CD);
}

// Round 5
// 1507.561 us; speedup vs baseline: 3.3640x; 1.0414x over previous
//
#include <hip/hip_runtime.h>
#include <cstdint>
#include <cstddef>

// ---------- constants ----------
#define CL 6
#define CH 12
#define CD 768
#define CDH 64
#define CF 3072
#define CV 32000
#define CS 1024
#define CB 2
#define CM (CB*CS)   // 2048 token rows
#define CQS 2304     // fused qkv row stride
#define PSTRIDE 4224 // partial: 64*64 O + 64 m + 64 l (floats)

typedef unsigned short u16;
typedef __bf16 bf16x8 __attribute__((ext_vector_type(8)));
typedef float f32x4 __attribute__((ext_vector_type(4)));

__device__ __forceinline__ float bf2f(u16 u) {
  union { unsigned int i; float f; } c; c.i = ((unsigned int)u) << 16; return c.f;
}
__device__ __forceinline__ u16 f2bf(float f) {
  union { float f; unsigned int i; } c; c.f = f;
  unsigned int lsb = (c.i >> 16) & 1u;
  c.i += 0x7fffu + lsb;            // round-to-nearest-even
  return (u16)(c.i >> 16);
}

// async global->LDS, 16B per lane; LDS dest = wave-uniform base + lane*16
__device__ __forceinline__ void gload16(const u16* g, u16* l) {
  __builtin_amdgcn_global_load_lds(
      (const __attribute__((address_space(1))) void*)g,
      (__attribute__((address_space(3))) void*)l, 16, 0, 0);
}

// ---------- fp32 -> bf16 convert (for head weight emb) ----------
__global__ __launch_bounds__(256) void convert_kernel(
    const float* __restrict__ src, u16* __restrict__ dst, int total)
{
  int idx = blockIdx.x * 256 + threadIdx.x;
  if (idx < total) dst[idx] = f2bf(src[idx]);
}

// ---------- embedding: x[m,d] = emb[X[m],d] + pos[s,d] (fp32 in/out) ----------
__global__ __launch_bounds__(256) void embed_kernel(
    const int* __restrict__ X, const float* __restrict__ emb,
    const float* __restrict__ pos, float* __restrict__ x)
{
  int idx = blockIdx.x * 256 + threadIdx.x;      // grid covers exactly CM*CD
  int m = idx / CD, d = idx - m * CD;
  int s = m & (CS - 1);
  x[idx] = emb[(size_t)X[m] * CD + d] + pos[s * CD + d];
}

// ---------- layernorm (fp32 in, bf16 out), one block per row, one pass ----------
__global__ __launch_bounds__(256) void ln_kernel(
    const float* __restrict__ x, const float* __restrict__ gs,
    const float* __restrict__ gb, u16* __restrict__ out)
{
  __shared__ float rs[4], rss[4];
  int row = blockIdx.x, tid = threadIdx.x;
  const float* xr = x + (size_t)row * CD;
  float a0 = xr[tid], a1 = xr[tid + 256], a2 = xr[tid + 512];
  float s = a0 + a1 + a2;
  float ss = a0 * a0 + a1 * a1 + a2 * a2;
#pragma unroll
  for (int sh = 32; sh > 0; sh >>= 1) {
    s  += __shfl_xor(s, sh, 64);
    ss += __shfl_xor(ss, sh, 64);
  }
  int w = tid >> 6;
  if ((tid & 63) == 0) { rs[w] = s; rss[w] = ss; }
  __syncthreads();
  s  = rs[0] + rs[1] + rs[2] + rs[3];
  ss = rss[0] + rss[1] + rss[2] + rss[3];
  float mu = s * (1.f / CD);
  float inv = rsqrtf(ss * (1.f / CD) - mu * mu + 1e-5f);
  u16* orow = out + (size_t)row * CD;
  orow[tid]       = f2bf((a0 - mu) * inv * gs[tid]       + gb[tid]);
  orow[tid + 256] = f2bf((a1 - mu) * inv * gs[tid + 256] + gb[tid + 256]);
  orow[tid + 512] = f2bf((a2 - mu) * inv * gs[tid + 512] + gb[tid + 512]);
}

// ---------- coalesced transpose repack: per z-batch dst[c][r] = bf16(src[r][c]) ----
__global__ __launch_bounds__(256) void trans_kernel(
    u16* __restrict__ dst, const float* __restrict__ src, int R, int C,
    int PB, long dstL)
{
  __shared__ float st[32][65];   // st[c][r]
  int r0 = blockIdx.x * 64, c0 = blockIdx.y * 32, bz = blockIdx.z;
  const float* s = src + (size_t)bz * R * C;
  u16* d = dst + (size_t)(bz / PB) * dstL + (size_t)(bz % PB) * R * C;
  int tx = threadIdx.x & 31, ty = threadIdx.x >> 5;
#pragma unroll
  for (int i = 0; i < 8; i++) {
    int r = ty + 8 * i;
    st[tx][r] = s[(size_t)(r0 + r) * C + c0 + tx];
  }
  __syncthreads();
  int j = threadIdx.x & 15, cbase = threadIdx.x >> 4;
#pragma unroll
  for (int i = 0; i < 2; i++) {
    int c = cbase + 16 * i;
    uint2 pk;
    u16* p = (u16*)&pk;
    p[0] = f2bf(st[c][4 * j + 0]);
    p[1] = f2bf(st[c][4 * j + 1]);
    p[2] = f2bf(st[c][4 * j + 2]);
    p[3] = f2bf(st[c][4 * j + 3]);
    *(uint2*)&d[(size_t)(c0 + c) * R + r0 + 4 * j] = pk;
  }
}

// ---------- pack per-layer qkv bias ----------
__global__ __launch_bounds__(256) void biaspack_kernel(
    const float* __restrict__ bq, const float* __restrict__ bk,
    const float* __restrict__ bv, float* __restrict__ dst)
{
  int idx = blockIdx.x * 256 + threadIdx.x;   // grid covers CL*2304 exactly
  int l = idx / CQS, c = idx - l * CQS;
  float val;
  if (c < 768)       val = bq[l * 768 + c];
  else if (c < 1536) val = bk[l * 768 + c - 768];
  else               val = bv[l * 768 + c - 1536];
  dst[idx] = val;
}

// ---------- MFMA GEMM 64x64, BK=32, global_load_lds staging (N=768 GEMMs) ------
template<bool RES, bool RELU, bool OUTBF>
__global__ __launch_bounds__(256) void gemm64v3_kernel(
    const u16* __restrict__ A, const u16* __restrict__ Bt,
    const float* __restrict__ bias, const float* __restrict__ res,
    void* __restrict__ outp, int M, int N, int K)
{
  __shared__ __align__(16) u16 As[64 * 32];
  __shared__ __align__(16) u16 Bs[64 * 32];
  int tid = threadIdx.x;
  int m0 = blockIdx.y * 64, n0 = blockIdx.x * 64;
  int wv = tid >> 6, ln = tid & 63;
  int quad = ln >> 4, l16 = ln & 15;
  int wm = (wv >> 1) * 32, wn = (wv & 1) * 32;
  int srow = tid >> 2, scol = (tid & 3) * 8;
  const u16* gA = A  + (size_t)(m0 + srow) * K + scol;
  const u16* gB = Bt + (size_t)(n0 + srow) * K + scol;
  u16* lA = As + wv * 512;
  u16* lB = Bs + wv * 512;

  f32x4 acc[2][2];
  acc[0][0] = f32x4{0,0,0,0}; acc[0][1] = f32x4{0,0,0,0};
  acc[1][0] = f32x4{0,0,0,0}; acc[1][1] = f32x4{0,0,0,0};

  for (int kt = 0; kt < K; kt += 32) {
    __syncthreads();
    gload16(gA + kt, lA);
    gload16(gB + kt, lB);
    __syncthreads();
    bf16x8 af[2], bfr[2];
#pragma unroll
    for (int i = 0; i < 2; i++) {
      af[i]  = *reinterpret_cast<const bf16x8*>(&As[(wm + i * 16 + l16) * 32 + quad * 8]);
      bfr[i] = *reinterpret_cast<const bf16x8*>(&Bs[(wn + i * 16 + l16) * 32 + quad * 8]);
    }
#pragma unroll
    for (int i = 0; i < 2; i++)
#pragma unroll
      for (int j = 0; j < 2; j++)
        acc[i][j] = __builtin_amdgcn_mfma_f32_16x16x32_bf16(af[i], bfr[j], acc[i][j], 0, 0, 0);
  }

#pragma unroll
  for (int i = 0; i < 2; i++) {
    int gmb = m0 + wm + i * 16 + quad * 4;
#pragma unroll
    for (int j = 0; j < 2; j++) {
      int gn = n0 + wn + j * 16 + l16;
      float bsv = bias[gn];
#pragma unroll
      for (int rr = 0; rr < 4; rr++) {
        float val = acc[i][j][rr] + bsv;
        if (RELU) val = fmaxf(val, 0.f);
        size_t o = (size_t)(gmb + rr) * N + gn;
        if (RES) val += res[o];
        if (OUTBF) ((u16*)outp)[o] = f2bf(val);
        else       ((float*)outp)[o] = val;
      }
    }
  }
}

// ---------- MFMA GEMM 128x128, BK=32, global_load_lds staging (m97 structure) ----
template<bool RES, bool RELU, bool OUTBF>
__global__ __launch_bounds__(256) void gemm128_kernel(
    const u16* __restrict__ A, const u16* __restrict__ Bt,
    const float* __restrict__ bias, const float* __restrict__ res,
    void* __restrict__ outp, int M, int N, int K)
{
  __shared__ __align__(16) u16 As[128 * 32];
  __shared__ __align__(16) u16 Bs[128 * 32];
  int tid = threadIdx.x;
  int nbm = M >> 7, nbn = N >> 7, nwg = nbm * nbn;
  int orig = blockIdx.x;
  int q8 = nwg >> 3, r8 = nwg & 7;
  int xcd = orig & 7;
  int t = ((xcd < r8) ? xcd * (q8 + 1) : r8 * (q8 + 1) + (xcd - r8) * q8) + (orig >> 3);
  int bm = t % nbm, bn = t / nbm;        // bn-major within chunk
  int m0 = bm << 7, n0 = bn << 7;

  int wv = tid >> 6, ln = tid & 63;
  int quad = ln >> 4, l16 = ln & 15;
  int wr = wv >> 1, wc = wv & 1;

  int srow = wv * 16 + (ln >> 2);
  int scol = (ln & 3) * 8;
  const u16* ga0 = A  + (size_t)(m0 + srow) * K + scol;
  const u16* ga1 = A  + (size_t)(m0 + srow + 64) * K + scol;
  const u16* gb0 = Bt + (size_t)(n0 + srow) * K + scol;
  const u16* gb1 = Bt + (size_t)(n0 + srow + 64) * K + scol;
  u16* lA0 = As + wv * 512;
  u16* lA1 = As + 2048 + wv * 512;
  u16* lB0 = Bs + wv * 512;
  u16* lB1 = Bs + 2048 + wv * 512;

  f32x4 acc[4][4];
#pragma unroll
  for (int i = 0; i < 4; i++)
#pragma unroll
    for (int j = 0; j < 4; j++) acc[i][j] = f32x4{0.f, 0.f, 0.f, 0.f};

  for (int kt = 0; kt < K; kt += 32) {
    __syncthreads();                  // prev iter's ds_reads done before overwrite
    gload16(ga0 + kt, lA0);
    gload16(ga1 + kt, lA1);
    gload16(gb0 + kt, lB0);
    gload16(gb1 + kt, lB1);
    __syncthreads();                  // implies vmcnt(0): staged data visible
    bf16x8 af[4], bf[4];
#pragma unroll
    for (int i = 0; i < 4; i++)
      af[i] = *reinterpret_cast<const bf16x8*>(&As[(wr * 64 + i * 16 + l16) * 32 + quad * 8]);
#pragma unroll
    for (int j = 0; j < 4; j++)
      bf[j] = *reinterpret_cast<const bf16x8*>(&Bs[(wc * 64 + j * 16 + l16) * 32 + quad * 8]);
#pragma unroll
    for (int i = 0; i < 4; i++)
#pragma unroll
      for (int j = 0; j < 4; j++)
        acc[i][j] = __builtin_amdgcn_mfma_f32_16x16x32_bf16(af[i], bf[j], acc[i][j], 0, 0, 0);
  }

#pragma unroll
  for (int i = 0; i < 4; i++) {
    int gm = m0 + wr * 64 + i * 16 + quad * 4;
#pragma unroll
    for (int j = 0; j < 4; j++) {
      int gn = n0 + wc * 64 + j * 16 + l16;
      float bsv = bias[gn];
#pragma unroll
      for (int rr = 0; rr < 4; rr++) {
        float val = acc[i][j][rr] + bsv;
        if (RELU) val = fmaxf(val, 0.f);
        size_t oo = (size_t)(gm + rr) * N + gn;
        if (RES) val += res[oo];
        if (OUTBF) ((u16*)outp)[oo] = f2bf(val);
        else       ((float*)outp)[oo] = val;
      }
    }
  }
}

// ---------- MFMA flash attention v3: split-KV flash-decoding ----------
// Tasks per (b,h): a=0..15 -> qb=15-(a>>1), two chunks (a even: upper, odd: lower);
// a=16..23 -> qb=23-a, full range. Split tasks write fp32 partials (O,m,l);
// attn_combine merges. Inner loop identical to harness-verified v2.
__global__ __launch_bounds__(256) void attn_mfma_kernel(
    const u16* __restrict__ qkv, u16* __restrict__ o, float* __restrict__ part)
{
  __shared__ __align__(16) u16 Ks[2][64 * 64];     // K tile  [t][d] swizzled
  __shared__ __align__(16) u16 Vt[2][64 * 64];     // V tile transposed [d][t] swizzled
  __shared__ __align__(16) u16 Ps[4 * 16 * 64];    // per-wave P [q][t] swizzled

  int tid = threadIdx.x;
  int a = blockIdx.x;                              // heavy chunks first
  int h = blockIdx.y, b = blockIdx.z;
  int wid = tid >> 6, lane = tid & 63, quad = lane >> 4, l16 = lane & 15;

  int qb, ts, te, chunk;
  if (a < 16) {
    qb = 15 - (a >> 1);
    int half = (qb + 1) >> 1;
    if (a & 1) { ts = 0; te = half - 1; chunk = 0; }
    else       { ts = half; te = qb;    chunk = 1; }
  } else { qb = 23 - a; ts = 0; te = qb; chunk = -1; }

  int q0 = qb * 64;
  size_t bh = (size_t)b * CS * CQS + h * CDH;      // fused layout [(b*S+s)*2304 + seg + h*64 + d]

  const u16* kbase = qkv + bh + 768;
  const u16* vbase = qkv + bh + 1536;

  // staging maps
  int t4 = (tid & 15) * 4, dg = (tid >> 4) * 4;    // V: 4 consecutive t rows x 4 d

  // Q A-fragments straight from global (one-time)
  bf16x8 aq[2];
  {
    const u16* qrow = qkv + bh + (size_t)(q0 + wid * 16 + l16) * CQS;
#pragma unroll
    for (int ks = 0; ks < 2; ks++) {
      uint4 t = *(const uint4*)(qrow + ks * 32 + quad * 8);
      aq[ks] = *reinterpret_cast<bf16x8*>(&t);
    }
  }

  f32x4 oacc[4];
  float mrow[4], lrow[4];
#pragma unroll
  for (int j = 0; j < 4; j++) oacc[j] = f32x4{0.f, 0.f, 0.f, 0.f};
#pragma unroll
  for (int r = 0; r < 4; r++) { mrow[r] = -1e30f; lrow[r] = 0.f; }

  // ---- prologue: stage tile ts into buf 0 ----
  {
    const u16* kb0 = kbase + (size_t)ts * 64 * CQS;
#pragma unroll
    for (int it = 0; it < 2; it++) {
      int c = it * 256 + tid;
      int row = c >> 3, c8l = c & 7;
      gload16(kb0 + (size_t)row * CQS + (((c8l ^ (row & 7)) * 8)),
              &Ks[0][(it * 256 + wid * 64) * 8]);
    }
    const u16* vb0 = vbase + (size_t)ts * 64 * CQS;
    uint2 vr[4];
#pragma unroll
    for (int i = 0; i < 4; i++)
      vr[i] = *(const uint2*)(vb0 + (size_t)(t4 + i) * CQS + dg);
#pragma unroll
    for (int j = 0; j < 4; j++) {
      int d = dg + j;
      uint2 pk;
      u16* p = (u16*)&pk;
      p[0] = ((const u16*)&vr[0])[j]; p[1] = ((const u16*)&vr[1])[j];
      p[2] = ((const u16*)&vr[2])[j]; p[3] = ((const u16*)&vr[3])[j];
      *(uint2*)&Vt[0][d * 64 + (((t4 >> 3) ^ (d & 7)) * 8) + (t4 & 4)] = pk;
    }
  }

  for (int tt = ts; tt <= te; tt++) {
    int t0 = tt * 64;
    int cur = (tt - ts) & 1;
    __syncthreads();   // buf[cur] staged (vmcnt+lds drained); buf[cur^1] free
    bool hasnext = (tt < te);
    uint2 vr[4];
    if (hasnext) {
      const u16* vb2 = vbase + (size_t)(t0 + 64) * CQS;
#pragma unroll
      for (int i = 0; i < 4; i++)
        vr[i] = *(const uint2*)(vb2 + (size_t)(t4 + i) * CQS + dg);
      const u16* kb2 = kbase + (size_t)(t0 + 64) * CQS;
#pragma unroll
      for (int it = 0; it < 2; it++) {
        int c = it * 256 + tid;
        int row = c >> 3, c8l = c & 7;
        gload16(kb2 + (size_t)row * CQS + (((c8l ^ (row & 7)) * 8)),
                &Ks[cur ^ 1][(it * 256 + wid * 64) * 8]);
      }
    }

    // ---- S = Q K^T (per wave: 16q x 64t) ----
    f32x4 sacc[4];
#pragma unroll
    for (int j = 0; j < 4; j++) sacc[j] = f32x4{0.f, 0.f, 0.f, 0.f};
#pragma unroll
    for (int j = 0; j < 4; j++) {
      int row = j * 16 + l16;
#pragma unroll
      for (int ks = 0; ks < 2; ks++) {
        bf16x8 bk = *reinterpret_cast<const bf16x8*>(
            &Ks[cur][row * 64 + ((((ks * 4 + quad) ^ (row & 7)) * 8))]);
        sacc[j] = __builtin_amdgcn_mfma_f32_16x16x32_bf16(aq[ks], bk, sacc[j], 0, 0, 0);
      }
    }

    // ---- scale + causal mask ----
    int qg0 = q0 + wid * 16 + quad * 4;   // q_glob for r=0
#pragma unroll
    for (int j = 0; j < 4; j++) {
      int tg = t0 + j * 16 + l16;
#pragma unroll
      for (int r = 0; r < 4; r++) {
        float s = sacc[j][r] * 0.125f;     // 1/sqrt(64)
        sacc[j][r] = (tg <= qg0 + r) ? s : -1e30f;
      }
    }

    // ---- online softmax ----
#pragma unroll
    for (int r = 0; r < 4; r++) {
      float m = fmaxf(fmaxf(sacc[0][r], sacc[1][r]), fmaxf(sacc[2][r], sacc[3][r]));
#pragma unroll
      for (int sh = 1; sh < 16; sh <<= 1) m = fmaxf(m, __shfl_xor(m, sh, 64));
      float mnew = fmaxf(mrow[r], m);
      float scal = __expf(mrow[r] - mnew);
      mrow[r] = mnew;
      lrow[r] *= scal;
#pragma unroll
      for (int j = 0; j < 4; j++) oacc[j][r] *= scal;
      float sum = 0.f;
#pragma unroll
      for (int j = 0; j < 4; j++) {
        float p = __expf(sacc[j][r] - mnew);
        sacc[j][r] = p;
        sum += p;
      }
#pragma unroll
      for (int sh = 1; sh < 16; sh <<= 1) sum += __shfl_xor(sum, sh, 64);
      lrow[r] += sum;
    }

    // ---- P -> LDS (bf16, per-wave region, swizzled; no barrier needed) ----
    u16* Pw = Ps + wid * 1024;
#pragma unroll
    for (int j = 0; j < 4; j++) {
      int c = (l16 >> 3) + 2 * j;
#pragma unroll
      for (int r = 0; r < 4; r++) {
        int row = quad * 4 + r;
        Pw[row * 64 + (((c ^ (row & 7)) * 8) | (l16 & 7))] = f2bf(sacc[j][r]);
      }
    }

    // ---- O += P V ----
    bf16x8 ap[2];
#pragma unroll
    for (int ks = 0; ks < 2; ks++)
      ap[ks] = *reinterpret_cast<const bf16x8*>(
          &Pw[l16 * 64 + ((((ks * 4 + quad) ^ (l16 & 7)) * 8))]);
#pragma unroll
    for (int j = 0; j < 4; j++) {
      int row = j * 16 + l16;
#pragma unroll
      for (int ks = 0; ks < 2; ks++) {
        bf16x8 bv = *reinterpret_cast<const bf16x8*>(
            &Vt[cur][row * 64 + ((((ks * 4 + quad) ^ (row & 7)) * 8))]);
        oacc[j] = __builtin_amdgcn_mfma_f32_16x16x32_bf16(ap[ks], bv, oacc[j], 0, 0, 0);
      }
    }

    // ---- V write-late into buf[cur^1] (completes before next top barrier) ----
    if (hasnext) {
#pragma unroll
      for (int j = 0; j < 4; j++) {
        int d = dg + j;
        uint2 pk;
        u16* p = (u16*)&pk;
        p[0] = ((const u16*)&vr[0])[j]; p[1] = ((const u16*)&vr[1])[j];
        p[2] = ((const u16*)&vr[2])[j]; p[3] = ((const u16*)&vr[3])[j];
        *(uint2*)&Vt[cur ^ 1][d * 64 + (((t4 >> 3) ^ (d & 7)) * 8) + (t4 & 4)] = pk;
      }
    }
  }

  if (chunk < 0) {
    // ---- full-range epilogue: O / l -> bf16 (output stride CD) ----
#pragma unroll
    for (int r = 0; r < 4; r++) {
      float inv = 1.f / lrow[r];
      int qg = q0 + wid * 16 + quad * 4 + r;
      u16* orow = o + (size_t)b * CS * CD + h * CDH + (size_t)qg * CD;
#pragma unroll
      for (int j = 0; j < 4; j++)
        orow[j * 16 + l16] = f2bf(oacc[j][r] * inv);
    }
  } else {
    // ---- partial epilogue: unnormalized O + m + l -> fp32 ----
    float* Po = part + (size_t)(((b * CH + h) * 8 + (qb - 8)) * 2 + chunk) * PSTRIDE;
#pragma unroll
    for (int r = 0; r < 4; r++) {
      int row = wid * 16 + quad * 4 + r;
#pragma unroll
      for (int j = 0; j < 4; j++)
        Po[row * 64 + j * 16 + l16] = oacc[j][r];
      if (l16 == 0) { Po[4096 + row] = mrow[r]; Po[4160 + row] = lrow[r]; }
    }
  }
}

// ---------- combine two KV-split partials -> bf16 output ----------
__global__ __launch_bounds__(256) void attn_combine_kernel(
    const float* __restrict__ part, u16* __restrict__ o)
{
  int qb = 8 + blockIdx.x, h = blockIdx.y, b = blockIdx.z;
  const float* P0 = part + (size_t)(((b * CH + h) * 8 + (qb - 8)) * 2) * PSTRIDE;
  const float* P1 = P0 + PSTRIDE;
  int t = threadIdx.x;
  int row = t >> 2, c0 = (t & 3) * 16;
  float m0 = P0[4096 + row], m1 = P1[4096 + row];
  float m = fmaxf(m0, m1);
  float w0 = __expf(m0 - m), w1 = __expf(m1 - m);
  float inv = 1.f / (P0[4160 + row] * w0 + P1[4160 + row] * w1);
  u16* orow = o + (size_t)b * CS * CD + h * CDH + (size_t)(qb * 64 + row) * CD;
#pragma unroll
  for (int j = 0; j < 16; j++) {
    int col = c0 + j;
    orow[col] = f2bf((P0[row * 64 + col] * w0 + P1[row * 64 + col] * w1) * inv);
  }
}

// ---------- launcher ----------
extern "C" void kernel_launch(void* const* d_in, const int* in_sizes, int n_in,
                              void* d_out, int out_size, void* d_ws, size_t ws_size,
                              hipStream_t stream) {
  const int*   X      = (const int*)d_in[0];
  const float* emb    = (const float*)d_in[1];
  const float* pos    = (const float*)d_in[2];
  const float* Wq     = (const float*)d_in[3];
  const float* bq     = (const float*)d_in[4];
  const float* Wk     = (const float*)d_in[5];
  const float* bk     = (const float*)d_in[6];
  const float* Wv     = (const float*)d_in[7];
  const float* bv     = (const float*)d_in[8];
  const float* Wo     = (const float*)d_in[9];
  const float* bo     = (const float*)d_in[10];
  const float* ln1s   = (const float*)d_in[11];
  const float* ln1b   = (const float*)d_in[12];
  const float* ln2s   = (const float*)d_in[13];
  const float* ln2b   = (const float*)d_in[14];
  const float* W1     = (const float*)d_in[15];
  const float* b1     = (const float*)d_in[16];
  const float* W2     = (const float*)d_in[17];
  const float* b2     = (const float*)d_in[18];
  const float* lnfs   = (const float*)d_in[19];
  const float* lnfb   = (const float*)d_in[20];
  const float* headb  = (const float*)d_in[21];
  (void)in_sizes; (void)n_in; (void)out_size;

  char* ws = (char*)d_ws;
  size_t off = 0;
  auto alloc = [&](size_t bytes) { void* p = ws + off; off += (bytes + 255) & ~(size_t)255; return p; };

  float* x     = (float*)alloc((size_t)CM * CD * 4);
  u16*   xn    = (u16*)  alloc((size_t)CM * CD * 2);
  u16*   qkvb  = (u16*)  alloc((size_t)CM * CQS * 2);
  u16*   ao    = (u16*)  alloc((size_t)CM * CD * 2);
  u16*   hb    = (u16*)  alloc((size_t)CM * CF * 2);
  u16*   embC  = (u16*)  alloc((size_t)CV * CD * 2);   // bf16 copy of emb for head GEMM
  float* biasp = (float*)alloc((size_t)CL * CQS * 4);  // fused qkv bias
  float* part  = (float*)alloc((size_t)CB * CH * 8 * 2 * PSTRIDE * 4);  // attn split partials

  const size_t WQKV = (size_t)CQS * CD;   // u16 elems per layer
  const size_t WOO  = (size_t)CD * CD;
  const size_t WFF  = (size_t)CD * CF;
  size_t perLayerElems = WQKV + WOO + 2 * WFF;
  bool fused = (ws_size >= off + (size_t)CL * perLayerElems * 2 + 4096);
  int LW = fused ? CL : 1;
  u16* Wqkvt = (u16*)alloc((size_t)LW * WQKV * 2);
  u16* Wot   = (u16*)alloc((size_t)LW * WOO * 2);
  u16* W1t   = (u16*)alloc((size_t)LW * WFF * 2);
  u16* W2t   = (u16*)alloc((size_t)LW * WFF * 2);

  embed_kernel<<<CM * CD / 256, 256, 0, stream>>>(X, emb, pos, x);
  convert_kernel<<<(CV * CD) / 256, 256, 0, stream>>>(emb, embC, CV * CD);
  biaspack_kernel<<<(CL * CQS) / 256, 256, 0, stream>>>(bq, bk, bv, biasp);

  if (fused) {
    trans_kernel<<<dim3(CD / 64, CDH / 32, CL * CH), 256, 0, stream>>>(Wqkvt,              Wq, CD, CDH, CH, (long)WQKV);
    trans_kernel<<<dim3(CD / 64, CDH / 32, CL * CH), 256, 0, stream>>>(Wqkvt + 768 * 768,  Wk, CD, CDH, CH, (long)WQKV);
    trans_kernel<<<dim3(CD / 64, CDH / 32, CL * CH), 256, 0, stream>>>(Wqkvt + 1536 * 768, Wv, CD, CDH, CH, (long)WQKV);
    trans_kernel<<<dim3(CD / 64, CD / 32, CL), 256, 0, stream>>>(Wot, Wo, CD, CD, 1, (long)WOO);
    trans_kernel<<<dim3(CD / 64, CF / 32, CL), 256, 0, stream>>>(W1t, W1, CD, CF, 1, (long)WFF);
    trans_kernel<<<dim3(CF / 64, CD / 32, CL), 256, 0, stream>>>(W2t, W2, CF, CD, 1, (long)WFF);
  }

  const int QKV_TOT = CH * CD * CDH;        // 589824

  for (int l = 0; l < CL; l++) {
    if (!fused) {
      trans_kernel<<<dim3(CD / 64, CDH / 32, CH), 256, 0, stream>>>(Wqkvt,              Wq + (size_t)l * QKV_TOT, CD, CDH, CH, (long)WQKV);
      trans_kernel<<<dim3(CD / 64, CDH / 32, CH), 256, 0, stream>>>(Wqkvt + 768 * 768,  Wk + (size_t)l * QKV_TOT, CD, CDH, CH, (long)WQKV);
      trans_kernel<<<dim3(CD / 64, CDH / 32, CH), 256, 0, stream>>>(Wqkvt + 1536 * 768, Wv + (size_t)l * QKV_TOT, CD, CDH, CH, (long)WQKV);
      trans_kernel<<<dim3(CD / 64, CD / 32, 1), 256, 0, stream>>>(Wot, Wo + (size_t)l * WOO, CD, CD, 1, (long)WOO);
      trans_kernel<<<dim3(CD / 64, CF / 32, 1), 256, 0, stream>>>(W1t, W1 + (size_t)l * WFF, CD, CF, 1, (long)WFF);
      trans_kernel<<<dim3(CF / 64, CD / 32, 1), 256, 0, stream>>>(W2t, W2 + (size_t)l * WFF, CF, CD, 1, (long)WFF);
    }
    int lw = fused ? l : 0;
    const u16* wqkv = Wqkvt + (size_t)lw * WQKV;
    const u16* wot  = Wot   + (size_t)lw * WOO;
    const u16* w1t  = W1t   + (size_t)lw * WFF;
    const u16* w2t  = W2t   + (size_t)lw * WFF;

    ln_kernel<<<CM, 256, 0, stream>>>(x, ln1s + l * CD, ln1b + l * CD, xn);

    gemm128_kernel<false, false, true><<<(CM / 128) * (CQS / 128), 256, 0, stream>>>(
        xn, wqkv, biasp + l * CQS, nullptr, qkvb, CM, CQS, CD);

    attn_mfma_kernel<<<dim3(24, CH, CB), 256, 0, stream>>>(qkvb, ao, part);
    attn_combine_kernel<<<dim3(8, CH, CB), 256, 0, stream>>>(part, ao);

    gemm64v3_kernel<true, false, false><<<dim3(CD / 64, CM / 64), 256, 0, stream>>>(
        ao, wot, bo + l * CD, x, x, CM, CD, CD);

    ln_kernel<<<CM, 256, 0, stream>>>(x, ln2s + l * CD, ln2b + l * CD, xn);

    gemm128_kernel<false, true, true><<<(CM / 128) * (CF / 128), 256, 0, stream>>>(
        xn, w1t, b1 + l * CF, nullptr, hb, CM, CF, CD);

    gemm64v3_kernel<true, false, false><<<dim3(CD / 64, CM / 64), 256, 0, stream>>>(
        hb, w2t, b2 + l * CD, x, x, CM, CD, CF);
  }

  ln_kernel<<<CM, 256, 0, stream>>>(x, lnfs, lnfb, xn);
  gemm128_kernel<false, false, false><<<(CM / 128) * (CV / 128), 256, 0, stream>>>(
      xn, embC, headb, nullptr, d_out, CM, CV, CD);
}

// Round 6
// 1475.717 us; speedup vs baseline: 3.4366x; 1.0216x over previous
//
#include <hip/hip_runtime.h>
#include <cstdint>
#include <cstddef>

// ---------- constants ----------
#define CL 6
#define CH 12
#define CD 768
#define CDH 64
#define CF 3072
#define CV 32000
#define CS 1024
#define CB 2
#define CM (CB*CS)   // 2048 token rows
#define CQS 2304     // fused qkv row stride
#define PSTRIDE 4224 // partial: 64*64 O + 64 m + 64 l (floats)

typedef unsigned short u16;
typedef __bf16 bf16x8 __attribute__((ext_vector_type(8)));
typedef float f32x4 __attribute__((ext_vector_type(4)));

__device__ __forceinline__ float bf2f(u16 u) {
  union { unsigned int i; float f; } c; c.i = ((unsigned int)u) << 16; return c.f;
}
__device__ __forceinline__ u16 f2bf(float f) {
  union { float f; unsigned int i; } c; c.f = f;
  unsigned int lsb = (c.i >> 16) & 1u;
  c.i += 0x7fffu + lsb;            // round-to-nearest-even
  return (u16)(c.i >> 16);
}

// async global->LDS, 16B per lane; LDS dest = wave-uniform base + lane*16
__device__ __forceinline__ void gload16(const u16* g, u16* l) {
  __builtin_amdgcn_global_load_lds(
      (const __attribute__((address_space(1))) void*)g,
      (__attribute__((address_space(3))) void*)l, 16, 0, 0);
}

// ---------- fp32 -> bf16 convert (for head weight emb) ----------
__global__ __launch_bounds__(256) void convert_kernel(
    const float* __restrict__ src, u16* __restrict__ dst, int total)
{
  int idx = blockIdx.x * 256 + threadIdx.x;
  if (idx < total) dst[idx] = f2bf(src[idx]);
}

// ---------- embedding: x[m,d] = emb[X[m],d] + pos[s,d] (fp32 in/out) ----------
__global__ __launch_bounds__(256) void embed_kernel(
    const int* __restrict__ X, const float* __restrict__ emb,
    const float* __restrict__ pos, float* __restrict__ x)
{
  int idx = blockIdx.x * 256 + threadIdx.x;      // grid covers exactly CM*CD
  int m = idx / CD, d = idx - m * CD;
  int s = m & (CS - 1);
  x[idx] = emb[(size_t)X[m] * CD + d] + pos[s * CD + d];
}

// ---------- layernorm (fp32 in, bf16 out), one block per row, one pass ----------
__global__ __launch_bounds__(256) void ln_kernel(
    const float* __restrict__ x, const float* __restrict__ gs,
    const float* __restrict__ gb, u16* __restrict__ out)
{
  __shared__ float rs[4], rss[4];
  int row = blockIdx.x, tid = threadIdx.x;
  const float* xr = x + (size_t)row * CD;
  float a0 = xr[tid], a1 = xr[tid + 256], a2 = xr[tid + 512];
  float s = a0 + a1 + a2;
  float ss = a0 * a0 + a1 * a1 + a2 * a2;
#pragma unroll
  for (int sh = 32; sh > 0; sh >>= 1) {
    s  += __shfl_xor(s, sh, 64);
    ss += __shfl_xor(ss, sh, 64);
  }
  int w = tid >> 6;
  if ((tid & 63) == 0) { rs[w] = s; rss[w] = ss; }
  __syncthreads();
  s  = rs[0] + rs[1] + rs[2] + rs[3];
  ss = rss[0] + rss[1] + rss[2] + rss[3];
  float mu = s * (1.f / CD);
  float inv = rsqrtf(ss * (1.f / CD) - mu * mu + 1e-5f);
  u16* orow = out + (size_t)row * CD;
  orow[tid]       = f2bf((a0 - mu) * inv * gs[tid]       + gb[tid]);
  orow[tid + 256] = f2bf((a1 - mu) * inv * gs[tid + 256] + gb[tid + 256]);
  orow[tid + 512] = f2bf((a2 - mu) * inv * gs[tid + 512] + gb[tid + 512]);
}

// ---------- coalesced transpose repack: per z-batch dst[c][r] = bf16(src[r][c]) ----
__global__ __launch_bounds__(256) void trans_kernel(
    u16* __restrict__ dst, const float* __restrict__ src, int R, int C,
    int PB, long dstL)
{
  __shared__ float st[32][65];   // st[c][r]
  int r0 = blockIdx.x * 64, c0 = blockIdx.y * 32, bz = blockIdx.z;
  const float* s = src + (size_t)bz * R * C;
  u16* d = dst + (size_t)(bz / PB) * dstL + (size_t)(bz % PB) * R * C;
  int tx = threadIdx.x & 31, ty = threadIdx.x >> 5;
#pragma unroll
  for (int i = 0; i < 8; i++) {
    int r = ty + 8 * i;
    st[tx][r] = s[(size_t)(r0 + r) * C + c0 + tx];
  }
  __syncthreads();
  int j = threadIdx.x & 15, cbase = threadIdx.x >> 4;
#pragma unroll
  for (int i = 0; i < 2; i++) {
    int c = cbase + 16 * i;
    uint2 pk;
    u16* p = (u16*)&pk;
    p[0] = f2bf(st[c][4 * j + 0]);
    p[1] = f2bf(st[c][4 * j + 1]);
    p[2] = f2bf(st[c][4 * j + 2]);
    p[3] = f2bf(st[c][4 * j + 3]);
    *(uint2*)&d[(size_t)(c0 + c) * R + r0 + 4 * j] = pk;
  }
}

// ---------- pack per-layer qkv bias ----------
__global__ __launch_bounds__(256) void biaspack_kernel(
    const float* __restrict__ bq, const float* __restrict__ bk,
    const float* __restrict__ bv, float* __restrict__ dst)
{
  int idx = blockIdx.x * 256 + threadIdx.x;   // grid covers CL*2304 exactly
  int l = idx / CQS, c = idx - l * CQS;
  float val;
  if (c < 768)       val = bq[l * 768 + c];
  else if (c < 1536) val = bk[l * 768 + c - 768];
  else               val = bv[l * 768 + c - 1536];
  dst[idx] = val;
}

// ---------- MFMA GEMM 64x64, BK=32, dbuf global_load_lds (N=768 GEMMs) ---------
// 2-phase pipeline: stage buf^1 BEFORE computing buf; ONE barrier per K-step.
template<bool RES, bool RELU, bool OUTBF>
__global__ __launch_bounds__(256) void gemm64v3_kernel(
    const u16* __restrict__ A, const u16* __restrict__ Bt,
    const float* __restrict__ bias, const float* __restrict__ res,
    void* __restrict__ outp, int M, int N, int K)
{
  __shared__ __align__(16) u16 As[2][64 * 32];
  __shared__ __align__(16) u16 Bs[2][64 * 32];
  int tid = threadIdx.x;
  int m0 = blockIdx.y * 64, n0 = blockIdx.x * 64;
  int wv = tid >> 6, ln = tid & 63;
  int quad = ln >> 4, l16 = ln & 15;
  int wm = (wv >> 1) * 32, wn = (wv & 1) * 32;
  int srow = tid >> 2, scol = (tid & 3) * 8;
  const u16* gA = A  + (size_t)(m0 + srow) * K + scol;
  const u16* gB = Bt + (size_t)(n0 + srow) * K + scol;

  f32x4 acc[2][2];
  acc[0][0] = f32x4{0,0,0,0}; acc[0][1] = f32x4{0,0,0,0};
  acc[1][0] = f32x4{0,0,0,0}; acc[1][1] = f32x4{0,0,0,0};

  // prologue: stage kt=0 into buf 0
  gload16(gA, &As[0][wv * 512]);
  gload16(gB, &Bs[0][wv * 512]);
  __syncthreads();
  int cur = 0;
  for (int kt = 0; kt < K; kt += 32) {
    if (kt + 32 < K) {
      gload16(gA + kt + 32, &As[cur ^ 1][wv * 512]);
      gload16(gB + kt + 32, &Bs[cur ^ 1][wv * 512]);
    }
    bf16x8 af[2], bfr[2];
#pragma unroll
    for (int i = 0; i < 2; i++) {
      af[i]  = *reinterpret_cast<const bf16x8*>(&As[cur][(wm + i * 16 + l16) * 32 + quad * 8]);
      bfr[i] = *reinterpret_cast<const bf16x8*>(&Bs[cur][(wn + i * 16 + l16) * 32 + quad * 8]);
    }
#pragma unroll
    for (int i = 0; i < 2; i++)
#pragma unroll
      for (int j = 0; j < 2; j++)
        acc[i][j] = __builtin_amdgcn_mfma_f32_16x16x32_bf16(af[i], bfr[j], acc[i][j], 0, 0, 0);
    __syncthreads();   // drains prefetch (vmcnt 0) + all reads of buf[cur] done
    cur ^= 1;
  }

#pragma unroll
  for (int i = 0; i < 2; i++) {
    int gmb = m0 + wm + i * 16 + quad * 4;
#pragma unroll
    for (int j = 0; j < 2; j++) {
      int gn = n0 + wn + j * 16 + l16;
      float bsv = bias[gn];
#pragma unroll
      for (int rr = 0; rr < 4; rr++) {
        float val = acc[i][j][rr] + bsv;
        if (RELU) val = fmaxf(val, 0.f);
        size_t o = (size_t)(gmb + rr) * N + gn;
        if (RES) val += res[o];
        if (OUTBF) ((u16*)outp)[o] = f2bf(val);
        else       ((float*)outp)[o] = val;
      }
    }
  }
}

// ---------- MFMA GEMM 128x128, BK=32, dbuf global_load_lds (QKV, FF1) ----------
template<bool RES, bool RELU, bool OUTBF>
__global__ __launch_bounds__(256) void gemm128_kernel(
    const u16* __restrict__ A, const u16* __restrict__ Bt,
    const float* __restrict__ bias, const float* __restrict__ res,
    void* __restrict__ outp, int M, int N, int K)
{
  __shared__ __align__(16) u16 As[2][128 * 32];
  __shared__ __align__(16) u16 Bs[2][128 * 32];
  int tid = threadIdx.x;
  int nbm = M >> 7, nbn = N >> 7, nwg = nbm * nbn;
  int orig = blockIdx.x;
  int q8 = nwg >> 3, r8 = nwg & 7;
  int xcd = orig & 7;
  int t = ((xcd < r8) ? xcd * (q8 + 1) : r8 * (q8 + 1) + (xcd - r8) * q8) + (orig >> 3);
  int bm = t % nbm, bn = t / nbm;        // bn-major within chunk
  int m0 = bm << 7, n0 = bn << 7;

  int wv = tid >> 6, ln = tid & 63;
  int quad = ln >> 4, l16 = ln & 15;
  int wr = wv >> 1, wc = wv & 1;

  int srow = wv * 16 + (ln >> 2);
  int scol = (ln & 3) * 8;
  const u16* ga0 = A  + (size_t)(m0 + srow) * K + scol;
  const u16* ga1 = A  + (size_t)(m0 + srow + 64) * K + scol;
  const u16* gb0 = Bt + (size_t)(n0 + srow) * K + scol;
  const u16* gb1 = Bt + (size_t)(n0 + srow + 64) * K + scol;

  f32x4 acc[4][4];
#pragma unroll
  for (int i = 0; i < 4; i++)
#pragma unroll
    for (int j = 0; j < 4; j++) acc[i][j] = f32x4{0.f, 0.f, 0.f, 0.f};

  // prologue: stage kt=0 into buf 0
  gload16(ga0, &As[0][wv * 512]);
  gload16(ga1, &As[0][2048 + wv * 512]);
  gload16(gb0, &Bs[0][wv * 512]);
  gload16(gb1, &Bs[0][2048 + wv * 512]);
  __syncthreads();
  int cur = 0;
  for (int kt = 0; kt < K; kt += 32) {
    if (kt + 32 < K) {
      gload16(ga0 + kt + 32, &As[cur ^ 1][wv * 512]);
      gload16(ga1 + kt + 32, &As[cur ^ 1][2048 + wv * 512]);
      gload16(gb0 + kt + 32, &Bs[cur ^ 1][wv * 512]);
      gload16(gb1 + kt + 32, &Bs[cur ^ 1][2048 + wv * 512]);
    }
    bf16x8 af[4], bf[4];
#pragma unroll
    for (int i = 0; i < 4; i++)
      af[i] = *reinterpret_cast<const bf16x8*>(&As[cur][(wr * 64 + i * 16 + l16) * 32 + quad * 8]);
#pragma unroll
    for (int j = 0; j < 4; j++)
      bf[j] = *reinterpret_cast<const bf16x8*>(&Bs[cur][(wc * 64 + j * 16 + l16) * 32 + quad * 8]);
#pragma unroll
    for (int i = 0; i < 4; i++)
#pragma unroll
      for (int j = 0; j < 4; j++)
        acc[i][j] = __builtin_amdgcn_mfma_f32_16x16x32_bf16(af[i], bf[j], acc[i][j], 0, 0, 0);
    __syncthreads();
    cur ^= 1;
  }

#pragma unroll
  for (int i = 0; i < 4; i++) {
    int gm = m0 + wr * 64 + i * 16 + quad * 4;
#pragma unroll
    for (int j = 0; j < 4; j++) {
      int gn = n0 + wc * 64 + j * 16 + l16;
      float bsv = bias[gn];
#pragma unroll
      for (int rr = 0; rr < 4; rr++) {
        float val = acc[i][j][rr] + bsv;
        if (RELU) val = fmaxf(val, 0.f);
        size_t oo = (size_t)(gm + rr) * N + gn;
        if (RES) val += res[oo];
        if (OUTBF) ((u16*)outp)[oo] = f2bf(val);
        else       ((float*)outp)[oo] = val;
      }
    }
  }
}

// ---------- MFMA GEMM 256x256, BK=64, dbuf, swizzled LDS (head GEMM) -----------
// 8 waves (2Mx4N), per-wave output 128x64. LDS 128 KB (1 block/CU).
// LDS rows are 128B -> 16-way bank conflict if linear; fixed with chunk^=(row&7)
// swizzle applied BOTH on the gload source address and the ds_read offset.
template<bool OUTBF>
__global__ __launch_bounds__(512, 2) void gemm256_kernel(
    const u16* __restrict__ A, const u16* __restrict__ Bt,
    const float* __restrict__ bias, void* __restrict__ outp,
    int M, int N, int K)
{
  __shared__ __align__(16) u16 As[2][256 * 64];   // 32 KB each
  __shared__ __align__(16) u16 Bs[2][256 * 64];
  int tid = threadIdx.x;
  int nbm = M >> 8, nbn = N >> 8, nwg = nbm * nbn;
  int orig = blockIdx.x;
  int q8 = nwg >> 3, r8 = nwg & 7;
  int xcd = orig & 7;
  int t = ((xcd < r8) ? xcd * (q8 + 1) : r8 * (q8 + 1) + (xcd - r8) * q8) + (orig >> 3);
  int bm = t % nbm, bn = t / nbm;        // bn-major: B tile reused across 8 m-blocks
  int m0 = bm << 8, n0 = bn << 8;

  int wv = tid >> 6, ln = tid & 63;
  int quad = ln >> 4, l16 = ln & 15;
  int wr = wv >> 2, wc = wv & 3;         // 2 x 4 wave grid

  // staging: 2048 16B-chunks per matrix per K-tile; thread covers chunk it*512+tid.
  // LDS linear chunk c holds global col8 = (c&7) ^ (row&7)  (row = c>>3).
  int srow = tid >> 3;                    // 0..63
  int scol = (((tid & 7) ^ (srow & 7)) * 8);
  const u16* gA = A  + (size_t)(m0 + srow) * K + scol;
  const u16* gB = Bt + (size_t)(n0 + srow) * K + scol;

  f32x4 acc[8][4];
#pragma unroll
  for (int i = 0; i < 8; i++)
#pragma unroll
    for (int j = 0; j < 4; j++) acc[i][j] = f32x4{0.f, 0.f, 0.f, 0.f};

  int nt = K >> 6;
  // prologue: stage K-tile 0 into buf 0
#pragma unroll
  for (int it = 0; it < 4; it++) {
    gload16(gA + (size_t)(it * 64) * K, &As[0][(it * 512 + wv * 64) * 8]);
    gload16(gB + (size_t)(it * 64) * K, &Bs[0][(it * 512 + wv * 64) * 8]);
  }
  __syncthreads();
  int cur = 0;
  for (int tt = 0; tt < nt; tt++) {
    if (tt + 1 < nt) {
      int kt = (tt + 1) << 6;
#pragma unroll
      for (int it = 0; it < 4; it++) {
        gload16(gA + (size_t)(it * 64) * K + kt, &As[cur ^ 1][(it * 512 + wv * 64) * 8]);
        gload16(gB + (size_t)(it * 64) * K + kt, &Bs[cur ^ 1][(it * 512 + wv * 64) * 8]);
      }
    }
    const u16* as = As[cur];
    const u16* bs = Bs[cur];
#pragma unroll
    for (int h = 0; h < 2; h++) {
      bf16x8 af[8], bf[4];
#pragma unroll
      for (int i = 0; i < 8; i++) {
        int R = wr * 128 + i * 16 + l16;
        af[i] = *reinterpret_cast<const bf16x8*>(&as[R * 64 + (((h * 4 + quad) ^ (R & 7)) * 8)]);
      }
#pragma unroll
      for (int j = 0; j < 4; j++) {
        int S = wc * 64 + j * 16 + l16;
        bf[j] = *reinterpret_cast<const bf16x8*>(&bs[S * 64 + (((h * 4 + quad) ^ (S & 7)) * 8)]);
      }
#pragma unroll
      for (int i = 0; i < 8; i++)
#pragma unroll
        for (int j = 0; j < 4; j++)
          acc[i][j] = __builtin_amdgcn_mfma_f32_16x16x32_bf16(af[i], bf[j], acc[i][j], 0, 0, 0);
    }
    __syncthreads();
    cur ^= 1;
  }

#pragma unroll
  for (int i = 0; i < 8; i++) {
    int gm = m0 + wr * 128 + i * 16 + quad * 4;
#pragma unroll
    for (int j = 0; j < 4; j++) {
      int gn = n0 + wc * 64 + j * 16 + l16;
      float bsv = bias[gn];
#pragma unroll
      for (int rr = 0; rr < 4; rr++) {
        float val = acc[i][j][rr] + bsv;
        size_t oo = (size_t)(gm + rr) * N + gn;
        if (OUTBF) ((u16*)outp)[oo] = f2bf(val);
        else       ((float*)outp)[oo] = val;
      }
    }
  }
}

// ---------- MFMA flash attention: split-KV + defer-max + setprio ----------
__global__ __launch_bounds__(256) void attn_mfma_kernel(
    const u16* __restrict__ qkv, u16* __restrict__ o, float* __restrict__ part)
{
  __shared__ __align__(16) u16 Ks[2][64 * 64];     // K tile  [t][d] swizzled
  __shared__ __align__(16) u16 Vt[2][64 * 64];     // V tile transposed [d][t] swizzled
  __shared__ __align__(16) u16 Ps[4 * 16 * 64];    // per-wave P [q][t] swizzled

  int tid = threadIdx.x;
  int a = blockIdx.x;                              // heavy chunks first
  int h = blockIdx.y, b = blockIdx.z;
  int wid = tid >> 6, lane = tid & 63, quad = lane >> 4, l16 = lane & 15;

  int qb, ts, te, chunk;
  if (a < 16) {
    qb = 15 - (a >> 1);
    int half = (qb + 1) >> 1;
    if (a & 1) { ts = 0; te = half - 1; chunk = 0; }
    else       { ts = half; te = qb;    chunk = 1; }
  } else { qb = 23 - a; ts = 0; te = qb; chunk = -1; }

  int q0 = qb * 64;
  size_t bh = (size_t)b * CS * CQS + h * CDH;      // fused layout [(b*S+s)*2304 + seg + h*64 + d]

  const u16* kbase = qkv + bh + 768;
  const u16* vbase = qkv + bh + 1536;

  // staging maps
  int t4 = (tid & 15) * 4, dg = (tid >> 4) * 4;    // V: 4 consecutive t rows x 4 d

  // Q A-fragments straight from global (one-time)
  bf16x8 aq[2];
  {
    const u16* qrow = qkv + bh + (size_t)(q0 + wid * 16 + l16) * CQS;
#pragma unroll
    for (int ks = 0; ks < 2; ks++) {
      uint4 t = *(const uint4*)(qrow + ks * 32 + quad * 8);
      aq[ks] = *reinterpret_cast<bf16x8*>(&t);
    }
  }

  f32x4 oacc[4];
  float mrow[4], lrow[4];
#pragma unroll
  for (int j = 0; j < 4; j++) oacc[j] = f32x4{0.f, 0.f, 0.f, 0.f};
#pragma unroll
  for (int r = 0; r < 4; r++) { mrow[r] = -1e30f; lrow[r] = 0.f; }

  // ---- prologue: stage tile ts into buf 0 ----
  {
    const u16* kb0 = kbase + (size_t)ts * 64 * CQS;
#pragma unroll
    for (int it = 0; it < 2; it++) {
      int c = it * 256 + tid;
      int row = c >> 3, c8l = c & 7;
      gload16(kb0 + (size_t)row * CQS + (((c8l ^ (row & 7)) * 8)),
              &Ks[0][(it * 256 + wid * 64) * 8]);
    }
    const u16* vb0 = vbase + (size_t)ts * 64 * CQS;
    uint2 vr[4];
#pragma unroll
    for (int i = 0; i < 4; i++)
      vr[i] = *(const uint2*)(vb0 + (size_t)(t4 + i) * CQS + dg);
#pragma unroll
    for (int j = 0; j < 4; j++) {
      int d = dg + j;
      uint2 pk;
      u16* p = (u16*)&pk;
      p[0] = ((const u16*)&vr[0])[j]; p[1] = ((const u16*)&vr[1])[j];
      p[2] = ((const u16*)&vr[2])[j]; p[3] = ((const u16*)&vr[3])[j];
      *(uint2*)&Vt[0][d * 64 + (((t4 >> 3) ^ (d & 7)) * 8) + (t4 & 4)] = pk;
    }
  }

  for (int tt = ts; tt <= te; tt++) {
    int t0 = tt * 64;
    int cur = (tt - ts) & 1;
    __syncthreads();   // buf[cur] staged (vmcnt+lds drained); buf[cur^1] free
    bool hasnext = (tt < te);
    uint2 vr[4];
    if (hasnext) {
      const u16* vb2 = vbase + (size_t)(t0 + 64) * CQS;
#pragma unroll
      for (int i = 0; i < 4; i++)
        vr[i] = *(const uint2*)(vb2 + (size_t)(t4 + i) * CQS + dg);
      const u16* kb2 = kbase + (size_t)(t0 + 64) * CQS;
#pragma unroll
      for (int it = 0; it < 2; it++) {
        int c = it * 256 + tid;
        int row = c >> 3, c8l = c & 7;
        gload16(kb2 + (size_t)row * CQS + (((c8l ^ (row & 7)) * 8)),
                &Ks[cur ^ 1][(it * 256 + wid * 64) * 8]);
      }
    }

    // ---- S = Q K^T (per wave: 16q x 64t) ----
    f32x4 sacc[4];
#pragma unroll
    for (int j = 0; j < 4; j++) sacc[j] = f32x4{0.f, 0.f, 0.f, 0.f};
    __builtin_amdgcn_s_setprio(1);
#pragma unroll
    for (int j = 0; j < 4; j++) {
      int row = j * 16 + l16;
#pragma unroll
      for (int ks = 0; ks < 2; ks++) {
        bf16x8 bk = *reinterpret_cast<const bf16x8*>(
            &Ks[cur][row * 64 + ((((ks * 4 + quad) ^ (row & 7)) * 8))]);
        sacc[j] = __builtin_amdgcn_mfma_f32_16x16x32_bf16(aq[ks], bk, sacc[j], 0, 0, 0);
      }
    }
    __builtin_amdgcn_s_setprio(0);

    // ---- scale + causal mask ----
    int qg0 = q0 + wid * 16 + quad * 4;   // q_glob for r=0
#pragma unroll
    for (int j = 0; j < 4; j++) {
      int tg = t0 + j * 16 + l16;
#pragma unroll
      for (int r = 0; r < 4; r++) {
        float s = sacc[j][r] * 0.125f;     // 1/sqrt(64)
        sacc[j][r] = (tg <= qg0 + r) ? s : -1e30f;
      }
    }

    // ---- online softmax with defer-max (THR=8; skip rescale if max ~flat) ----
    float tmax[4];
#pragma unroll
    for (int r = 0; r < 4; r++) {
      float m = fmaxf(fmaxf(sacc[0][r], sacc[1][r]), fmaxf(sacc[2][r], sacc[3][r]));
#pragma unroll
      for (int sh = 1; sh < 16; sh <<= 1) m = fmaxf(m, __shfl_xor(m, sh, 64));
      tmax[r] = m;
    }
    bool grow = (tmax[0] > mrow[0] + 8.f) || (tmax[1] > mrow[1] + 8.f) ||
                (tmax[2] > mrow[2] + 8.f) || (tmax[3] > mrow[3] + 8.f);
    if (__any(grow)) {
#pragma unroll
      for (int r = 0; r < 4; r++) {
        float mnew = fmaxf(mrow[r], tmax[r]);
        float scal = __expf(mrow[r] - mnew);
        mrow[r] = mnew;
        lrow[r] *= scal;
#pragma unroll
        for (int j = 0; j < 4; j++) oacc[j][r] *= scal;
      }
    }
#pragma unroll
    for (int r = 0; r < 4; r++) {
      float sum = 0.f;
#pragma unroll
      for (int j = 0; j < 4; j++) {
        float p = __expf(sacc[j][r] - mrow[r]);
        sacc[j][r] = p;
        sum += p;
      }
#pragma unroll
      for (int sh = 1; sh < 16; sh <<= 1) sum += __shfl_xor(sum, sh, 64);
      lrow[r] += sum;
    }

    // ---- P -> LDS (bf16, per-wave region, swizzled; no barrier needed) ----
    u16* Pw = Ps + wid * 1024;
#pragma unroll
    for (int j = 0; j < 4; j++) {
      int c = (l16 >> 3) + 2 * j;
#pragma unroll
      for (int r = 0; r < 4; r++) {
        int row = quad * 4 + r;
        Pw[row * 64 + (((c ^ (row & 7)) * 8) | (l16 & 7))] = f2bf(sacc[j][r]);
      }
    }

    // ---- O += P V ----
    bf16x8 ap[2];
#pragma unroll
    for (int ks = 0; ks < 2; ks++)
      ap[ks] = *reinterpret_cast<const bf16x8*>(
          &Pw[l16 * 64 + ((((ks * 4 + quad) ^ (l16 & 7)) * 8))]);
    __builtin_amdgcn_s_setprio(1);
#pragma unroll
    for (int j = 0; j < 4; j++) {
      int row = j * 16 + l16;
#pragma unroll
      for (int ks = 0; ks < 2; ks++) {
        bf16x8 bv = *reinterpret_cast<const bf16x8*>(
            &Vt[cur][row * 64 + ((((ks * 4 + quad) ^ (row & 7)) * 8))]);
        oacc[j] = __builtin_amdgcn_mfma_f32_16x16x32_bf16(ap[ks], bv, oacc[j], 0, 0, 0);
      }
    }
    __builtin_amdgcn_s_setprio(0);

    // ---- V write-late into buf[cur^1] (completes before next top barrier) ----
    if (hasnext) {
#pragma unroll
      for (int j = 0; j < 4; j++) {
        int d = dg + j;
        uint2 pk;
        u16* p = (u16*)&pk;
        p[0] = ((const u16*)&vr[0])[j]; p[1] = ((const u16*)&vr[1])[j];
        p[2] = ((const u16*)&vr[2])[j]; p[3] = ((const u16*)&vr[3])[j];
        *(uint2*)&Vt[cur ^ 1][d * 64 + (((t4 >> 3) ^ (d & 7)) * 8) + (t4 & 4)] = pk;
      }
    }
  }

  if (chunk < 0) {
    // ---- full-range epilogue: O / l -> bf16 (output stride CD) ----
#pragma unroll
    for (int r = 0; r < 4; r++) {
      float inv = 1.f / lrow[r];
      int qg = q0 + wid * 16 + quad * 4 + r;
      u16* orow = o + (size_t)b * CS * CD + h * CDH + (size_t)qg * CD;
#pragma unroll
      for (int j = 0; j < 4; j++)
        orow[j * 16 + l16] = f2bf(oacc[j][r] * inv);
    }
  } else {
    // ---- partial epilogue: unnormalized O + m + l -> fp32 ----
    float* Po = part + (size_t)(((b * CH + h) * 8 + (qb - 8)) * 2 + chunk) * PSTRIDE;
#pragma unroll
    for (int r = 0; r < 4; r++) {
      int row = wid * 16 + quad * 4 + r;
#pragma unroll
      for (int j = 0; j < 4; j++)
        Po[row * 64 + j * 16 + l16] = oacc[j][r];
      if (l16 == 0) { Po[4096 + row] = mrow[r]; Po[4160 + row] = lrow[r]; }
    }
  }
}

// ---------- combine two KV-split partials -> bf16 output ----------
__global__ __launch_bounds__(256) void attn_combine_kernel(
    const float* __restrict__ part, u16* __restrict__ o)
{
  int qb = 8 + blockIdx.x, h = blockIdx.y, b = blockIdx.z;
  const float* P0 = part + (size_t)(((b * CH + h) * 8 + (qb - 8)) * 2) * PSTRIDE;
  const float* P1 = P0 + PSTRIDE;
  int t = threadIdx.x;
  int row = t >> 2, c0 = (t & 3) * 16;
  float m0 = P0[4096 + row], m1 = P1[4096 + row];
  float m = fmaxf(m0, m1);
  float w0 = __expf(m0 - m), w1 = __expf(m1 - m);
  float inv = 1.f / (P0[4160 + row] * w0 + P1[4160 + row] * w1);
  u16* orow = o + (size_t)b * CS * CD + h * CDH + (size_t)(qb * 64 + row) * CD;
#pragma unroll
  for (int j = 0; j < 16; j++) {
    int col = c0 + j;
    orow[col] = f2bf((P0[row * 64 + col] * w0 + P1[row * 64 + col] * w1) * inv);
  }
}

// ---------- launcher ----------
extern "C" void kernel_launch(void* const* d_in, const int* in_sizes, int n_in,
                              void* d_out, int out_size, void* d_ws, size_t ws_size,
                              hipStream_t stream) {
  const int*   X      = (const int*)d_in[0];
  const float* emb    = (const float*)d_in[1];
  const float* pos    = (const float*)d_in[2];
  const float* Wq     = (const float*)d_in[3];
  const float* bq     = (const float*)d_in[4];
  const float* Wk     = (const float*)d_in[5];
  const float* bk     = (const float*)d_in[6];
  const float* Wv     = (const float*)d_in[7];
  const float* bv     = (const float*)d_in[8];
  const float* Wo     = (const float*)d_in[9];
  const float* bo     = (const float*)d_in[10];
  const float* ln1s   = (const float*)d_in[11];
  const float* ln1b   = (const float*)d_in[12];
  const float* ln2s   = (const float*)d_in[13];
  const float* ln2b   = (const float*)d_in[14];
  const float* W1     = (const float*)d_in[15];
  const float* b1     = (const float*)d_in[16];
  const float* W2     = (const float*)d_in[17];
  const float* b2     = (const float*)d_in[18];
  const float* lnfs   = (const float*)d_in[19];
  const float* lnfb   = (const float*)d_in[20];
  const float* headb  = (const float*)d_in[21];
  (void)in_sizes; (void)n_in; (void)out_size;

  char* ws = (char*)d_ws;
  size_t off = 0;
  auto alloc = [&](size_t bytes) { void* p = ws + off; off += (bytes + 255) & ~(size_t)255; return p; };

  float* x     = (float*)alloc((size_t)CM * CD * 4);
  u16*   xn    = (u16*)  alloc((size_t)CM * CD * 2);
  u16*   qkvb  = (u16*)  alloc((size_t)CM * CQS * 2);
  u16*   ao    = (u16*)  alloc((size_t)CM * CD * 2);
  u16*   hb    = (u16*)  alloc((size_t)CM * CF * 2);
  u16*   embC  = (u16*)  alloc((size_t)CV * CD * 2);   // bf16 copy of emb for head GEMM
  float* biasp = (float*)alloc((size_t)CL * CQS * 4);  // fused qkv bias
  float* part  = (float*)alloc((size_t)CB * CH * 8 * 2 * PSTRIDE * 4);  // attn split partials

  const size_t WQKV = (size_t)CQS * CD;   // u16 elems per layer
  const size_t WOO  = (size_t)CD * CD;
  const size_t WFF  = (size_t)CD * CF;
  size_t perLayerElems = WQKV + WOO + 2 * WFF;
  bool fused = (ws_size >= off + (size_t)CL * perLayerElems * 2 + 4096);
  int LW = fused ? CL : 1;
  u16* Wqkvt = (u16*)alloc((size_t)LW * WQKV * 2);
  u16* Wot   = (u16*)alloc((size_t)LW * WOO * 2);
  u16* W1t   = (u16*)alloc((size_t)LW * WFF * 2);
  u16* W2t   = (u16*)alloc((size_t)LW * WFF * 2);

  embed_kernel<<<CM * CD / 256, 256, 0, stream>>>(X, emb, pos, x);
  convert_kernel<<<(CV * CD) / 256, 256, 0, stream>>>(emb, embC, CV * CD);
  biaspack_kernel<<<(CL * CQS) / 256, 256, 0, stream>>>(bq, bk, bv, biasp);

  if (fused) {
    trans_kernel<<<dim3(CD / 64, CDH / 32, CL * CH), 256, 0, stream>>>(Wqkvt,              Wq, CD, CDH, CH, (long)WQKV);
    trans_kernel<<<dim3(CD / 64, CDH / 32, CL * CH), 256, 0, stream>>>(Wqkvt + 768 * 768,  Wk, CD, CDH, CH, (long)WQKV);
    trans_kernel<<<dim3(CD / 64, CDH / 32, CL * CH), 256, 0, stream>>>(Wqkvt + 1536 * 768, Wv, CD, CDH, CH, (long)WQKV);
    trans_kernel<<<dim3(CD / 64, CD / 32, CL), 256, 0, stream>>>(Wot, Wo, CD, CD, 1, (long)WOO);
    trans_kernel<<<dim3(CD / 64, CF / 32, CL), 256, 0, stream>>>(W1t, W1, CD, CF, 1, (long)WFF);
    trans_kernel<<<dim3(CF / 64, CD / 32, CL), 256, 0, stream>>>(W2t, W2, CF, CD, 1, (long)WFF);
  }

  const int QKV_TOT = CH * CD * CDH;        // 589824

  for (int l = 0; l < CL; l++) {
    if (!fused) {
      trans_kernel<<<dim3(CD / 64, CDH / 32, CH), 256, 0, stream>>>(Wqkvt,              Wq + (size_t)l * QKV_TOT, CD, CDH, CH, (long)WQKV);
      trans_kernel<<<dim3(CD / 64, CDH / 32, CH), 256, 0, stream>>>(Wqkvt + 768 * 768,  Wk + (size_t)l * QKV_TOT, CD, CDH, CH, (long)WQKV);
      trans_kernel<<<dim3(CD / 64, CDH / 32, CH), 256, 0, stream>>>(Wqkvt + 1536 * 768, Wv + (size_t)l * QKV_TOT, CD, CDH, CH, (long)WQKV);
      trans_kernel<<<dim3(CD / 64, CD / 32, 1), 256, 0, stream>>>(Wot, Wo + (size_t)l * WOO, CD, CD, 1, (long)WOO);
      trans_kernel<<<dim3(CD / 64, CF / 32, 1), 256, 0, stream>>>(W1t, W1 + (size_t)l * WFF, CD, CF, 1, (long)WFF);
      trans_kernel<<<dim3(CF / 64, CD / 32, 1), 256, 0, stream>>>(W2t, W2 + (size_t)l * WFF, CF, CD, 1, (long)WFF);
    }
    int lw = fused ? l : 0;
    const u16* wqkv = Wqkvt + (size_t)lw * WQKV;
    const u16* wot  = Wot   + (size_t)lw * WOO;
    const u16* w1t  = W1t   + (size_t)lw * WFF;
    const u16* w2t  = W2t   + (size_t)lw * WFF;

    ln_kernel<<<CM, 256, 0, stream>>>(x, ln1s + l * CD, ln1b + l * CD, xn);

    gemm128_kernel<false, false, true><<<(CM / 128) * (CQS / 128), 256, 0, stream>>>(
        xn, wqkv, biasp + l * CQS, nullptr, qkvb, CM, CQS, CD);

    attn_mfma_kernel<<<dim3(24, CH, CB), 256, 0, stream>>>(qkvb, ao, part);
    attn_combine_kernel<<<dim3(8, CH, CB), 256, 0, stream>>>(part, ao);

    gemm64v3_kernel<true, false, false><<<dim3(CD / 64, CM / 64), 256, 0, stream>>>(
        ao, wot, bo + l * CD, x, x, CM, CD, CD);

    ln_kernel<<<CM, 256, 0, stream>>>(x, ln2s + l * CD, ln2b + l * CD, xn);

    gemm128_kernel<false, true, true><<<(CM / 128) * (CF / 128), 256, 0, stream>>>(
        xn, w1t, b1 + l * CF, nullptr, hb, CM, CF, CD);

    gemm64v3_kernel<true, false, false><<<dim3(CD / 64, CM / 64), 256, 0, stream>>>(
        hb, w2t, b2 + l * CD, x, x, CM, CD, CF);
  }

  ln_kernel<<<CM, 256, 0, stream>>>(x, lnfs, lnfb, xn);
  gemm256_kernel<false><<<(CM / 256) * (CV / 256), 512, 0, stream>>>(
      xn, embC, headb, d_out, CM, CV, CD);
}